// Round 3
// baseline (577.730 us; speedup 1.0000x reference)
//
#include <hip/hip_runtime.h>

typedef unsigned short u16;
typedef short s16x8 __attribute__((ext_vector_type(8)));
typedef float f32x4 __attribute__((ext_vector_type(4)));

__device__ __forceinline__ u16 f2b(float f){
  union { float f; unsigned int i; } v; v.f = f;
  unsigned int r = v.i + 0x7FFFu + ((v.i >> 16) & 1u);
  return (u16)(r >> 16);
}

// ---------------- transpose+convert: in f32 [K][N] -> out bf16 [N][K] ----------------
__global__ __launch_bounds__(256) void transpose_k(const float* __restrict__ in,
                                                   u16* __restrict__ out, int K, int N)
{
  __shared__ u16 tile[32][33];
  const int tx = threadIdx.x, ty = threadIdx.y;
  const int x = blockIdx.x * 32 + tx;
  const int y0 = blockIdx.y * 32;
  #pragma unroll
  for (int j = ty; j < 32; j += 8)
    tile[j][tx] = f2b(in[(size_t)(y0 + j) * N + x]);
  __syncthreads();
  const int x2 = y0 + tx;
  const int y2 = blockIdx.x * 32;
  #pragma unroll
  for (int j = ty; j < 32; j += 8)
    out[(size_t)(y2 + j) * K + x2] = tile[tx][j];
}

// ---------------- layernorm: f32 in, bf16 out; one block per row of 1024 ----------------
__global__ __launch_bounds__(256) void ln_k(const float* __restrict__ xin,
                                            const float* __restrict__ g,
                                            const float* __restrict__ be,
                                            u16* __restrict__ out)
{
  const int row = blockIdx.x, tid = threadIdx.x;
  float4 u = *(const float4*)(xin + (size_t)row * 1024 + tid * 4);
  float v[4] = {u.x, u.y, u.z, u.w};
  float sum = v[0] + v[1] + v[2] + v[3];
  float sq  = v[0]*v[0] + v[1]*v[1] + v[2]*v[2] + v[3]*v[3];
  #pragma unroll
  for (int off = 32; off > 0; off >>= 1) {
    sum += __shfl_down(sum, off, 64);
    sq  += __shfl_down(sq,  off, 64);
  }
  __shared__ float ws1[4], ws2[4];
  const int wid = tid >> 6, lane = tid & 63;
  if (lane == 0) { ws1[wid] = sum; ws2[wid] = sq; }
  __syncthreads();
  const float tot  = ws1[0] + ws1[1] + ws1[2] + ws1[3];
  const float tot2 = ws2[0] + ws2[1] + ws2[2] + ws2[3];
  const float inv = 1.0f / 1024.0f;
  const float mu = tot * inv;
  const float var = tot2 * inv - mu * mu;
  const float rs = rsqrtf(var + 1e-5f);
  float4 gv = *(const float4*)(g  + tid * 4);
  float4 bv = *(const float4*)(be + tid * 4);
  u16 ob[4];
  ob[0] = f2b((v[0] - mu) * rs * gv.x + bv.x);
  ob[1] = f2b((v[1] - mu) * rs * gv.y + bv.y);
  ob[2] = f2b((v[2] - mu) * rs * gv.z + bv.z);
  ob[3] = f2b((v[3] - mu) * rs * gv.w + bv.w);
  uint2 o;
  o.x = (unsigned)ob[0] | ((unsigned)ob[1] << 16);
  o.y = (unsigned)ob[2] | ((unsigned)ob[3] << 16);
  *(uint2*)(out + (size_t)row * 1024 + tid * 4) = o;
}

// ---- GEMM: C[.,N] = act(A[.,K](lda) @ Bt[N,K](ldb)^T + bias) (+f32 res), C pitch ldc ----
// ACT: 0 none, 1 exact GELU. RES: add f32 res[idx]. OUTF: write f32 else bf16.
// bias may be nullptr (treated as 0).
template<int ACT, bool RES, bool OUTF>
__global__ __launch_bounds__(256) void gemm_bt(const u16* __restrict__ A, int lda,
                                               const u16* __restrict__ Bt, int ldb,
                                               const float* __restrict__ bias,
                                               const float* __restrict__ res,
                                               void* __restrict__ Cout,
                                               int K, int ldc)
{
  constexpr int BK = 64, PAD = 8;
  __shared__ __align__(16) u16 As[128][BK + PAD];
  __shared__ __align__(16) u16 Bs[128][BK + PAD];
  const int tid = threadIdx.x;
  const int wid = tid >> 6, lane = tid & 63, quad = lane >> 4, ln = lane & 15;
  const int wr = wid >> 1, wc = wid & 1;
  const int m0 = blockIdx.y * 128, n0 = blockIdx.x * 128;

  f32x4 acc[4][4];
  #pragma unroll
  for (int i = 0; i < 4; ++i)
    #pragma unroll
    for (int j = 0; j < 4; ++j)
      #pragma unroll
      for (int r = 0; r < 4; ++r) acc[i][j][r] = 0.f;

  const int sr = tid >> 3;         // 0..31
  const int sc = (tid & 7) * 8;    // 0..56

  for (int k0 = 0; k0 < K; k0 += BK) {
    #pragma unroll
    for (int p = 0; p < 4; ++p) {
      const int row = sr + p * 32;
      *(s16x8*)&As[row][sc] = *(const s16x8*)&A [(size_t)(m0 + row) * lda + k0 + sc];
      *(s16x8*)&Bs[row][sc] = *(const s16x8*)&Bt[(size_t)(n0 + row) * ldb + k0 + sc];
    }
    __syncthreads();
    #pragma unroll
    for (int ks = 0; ks < 2; ++ks) {
      s16x8 af[4], bfr[4];
      #pragma unroll
      for (int i = 0; i < 4; ++i) af[i]  = *(const s16x8*)&As[wr*64 + i*16 + ln][ks*32 + quad*8];
      #pragma unroll
      for (int j = 0; j < 4; ++j) bfr[j] = *(const s16x8*)&Bs[wc*64 + j*16 + ln][ks*32 + quad*8];
      #pragma unroll
      for (int i = 0; i < 4; ++i)
        #pragma unroll
        for (int j = 0; j < 4; ++j)
          acc[i][j] = __builtin_amdgcn_mfma_f32_16x16x32_bf16(af[i], bfr[j], acc[i][j], 0, 0, 0);
    }
    __syncthreads();
  }

  float bv[4];
  #pragma unroll
  for (int j = 0; j < 4; ++j) bv[j] = bias ? bias[n0 + wc*64 + j*16 + ln] : 0.f;

  #pragma unroll
  for (int i = 0; i < 4; ++i) {
    #pragma unroll
    for (int r = 0; r < 4; ++r) {
      const int row = m0 + wr*64 + i*16 + quad*4 + r;
      #pragma unroll
      for (int j = 0; j < 4; ++j) {
        const int col = n0 + wc*64 + j*16 + ln;
        const size_t idx = (size_t)row * ldc + col;
        float v = acc[i][j][r] + bv[j];
        if (RES) v += res[idx];
        if (ACT == 1) v = 0.5f * v * (1.f + erff(v * 0.70710678118f));
        if (OUTF) ((float*)Cout)[idx] = v;
        else      ((u16*)Cout)[idx] = f2b(v);
      }
    }
  }
}

// ---------------- flash attention: one wave per (b, h, 16 q-rows), bf16 in/out ----------------
__global__ __launch_bounds__(256) void attn_k(const u16* __restrict__ qkv,
                                              u16* __restrict__ outp)
{
  __shared__ __align__(16) u16 Pbuf[4][16][40];
  __shared__ __align__(16) u16 Vt[4][64][40];
  const int tid = threadIdx.x, wid = tid >> 6, lane = tid & 63;
  const int quad = lane >> 4, ln = lane & 15;
  const int blk = blockIdx.x, bh = blk >> 5, qt = blk & 31, b = bh >> 4, h = bh & 15;
  const int q0 = qt * 64 + wid * 16;
  const u16* base = qkv + (size_t)b * 2048 * 3072;

  s16x8 aQ[2];
  {
    const u16* qrow = base + (size_t)(q0 + ln) * 3072 + h * 64;
    aQ[0] = *(const s16x8*)(qrow + quad * 8);
    aQ[1] = *(const s16x8*)(qrow + 32 + quad * 8);
  }
  f32x4 o[4];
  float mi[4], li[4];
  #pragma unroll
  for (int j = 0; j < 4; ++j) {
    mi[j] = -1e30f; li[j] = 0.f;
    #pragma unroll
    for (int r = 0; r < 4; ++r) o[j][r] = 0.f;
  }
  const float scale = 0.125f;                 // 1/sqrt(64)
  const int nkt = qt * 2 + 2;                 // uniform across the block's 4 waves

  for (int kt = 0; kt < nkt; ++kt) {
    const int kb = kt * 32;
    f32x4 s0, s1;
    #pragma unroll
    for (int r = 0; r < 4; ++r) { s0[r] = 0.f; s1[r] = 0.f; }
    #pragma unroll
    for (int ks = 0; ks < 2; ++ks) {
      const u16* k0p = base + (size_t)(kb + ln)      * 3072 + 1024 + h*64 + ks*32 + quad*8;
      const u16* k1p = base + (size_t)(kb + 16 + ln) * 3072 + 1024 + h*64 + ks*32 + quad*8;
      s16x8 bK0 = *(const s16x8*)k0p;
      s16x8 bK1 = *(const s16x8*)k1p;
      s0 = __builtin_amdgcn_mfma_f32_16x16x32_bf16(aQ[ks], bK0, s0, 0, 0, 0);
      s1 = __builtin_amdgcn_mfma_f32_16x16x32_bf16(aQ[ks], bK1, s1, 0, 0, 0);
    }
    float mnew[4], alpha[4], rsum[4];
    #pragma unroll
    for (int r = 0; r < 4; ++r) {
      const int q = q0 + quad * 4 + r;
      float v0 = s0[r] * scale; if (kb + ln > q)      v0 = -1e30f;
      float v1 = s1[r] * scale; if (kb + 16 + ln > q) v1 = -1e30f;
      s0[r] = v0; s1[r] = v1;
      mnew[r] = fmaxf(v0, v1);
    }
    #pragma unroll
    for (int off = 1; off < 16; off <<= 1)
      #pragma unroll
      for (int r = 0; r < 4; ++r) mnew[r] = fmaxf(mnew[r], __shfl_xor(mnew[r], off, 64));
    #pragma unroll
    for (int r = 0; r < 4; ++r) {
      mnew[r] = fmaxf(mnew[r], mi[r]);   // finite after tile 0 (key 0 always unmasked)
      alpha[r] = __expf(mi[r] - mnew[r]);
      float p0 = __expf(s0[r] - mnew[r]);
      float p1 = __expf(s1[r] - mnew[r]);
      s0[r] = p0; s1[r] = p1; rsum[r] = p0 + p1; mi[r] = mnew[r];
    }
    #pragma unroll
    for (int off = 1; off < 16; off <<= 1)
      #pragma unroll
      for (int r = 0; r < 4; ++r) rsum[r] += __shfl_xor(rsum[r], off, 64);
    #pragma unroll
    for (int r = 0; r < 4; ++r) li[r] = li[r] * alpha[r] + rsum[r];
    #pragma unroll
    for (int j = 0; j < 4; ++j)
      #pragma unroll
      for (int r = 0; r < 4; ++r) o[j][r] *= alpha[r];

    __syncthreads();   // previous iteration's LDS reads complete before overwrite

    // P (C-layout) -> LDS bf16 (A-layout source)
    #pragma unroll
    for (int r = 0; r < 4; ++r) {
      Pbuf[wid][quad*4 + r][ln]      = f2b(s0[r]);
      Pbuf[wid][quad*4 + r][16 + ln] = f2b(s1[r]);
    }
    // stage V transposed: Vt[dim][key]
    {
      const int kr = lane >> 1, half = lane & 1;
      const u16* vrow = base + (size_t)(kb + kr) * 3072 + 2048 + h*64 + half*32;
      #pragma unroll
      for (int e = 0; e < 32; e += 8) {
        s16x8 v = *(const s16x8*)(vrow + e);
        #pragma unroll
        for (int t = 0; t < 8; ++t) Vt[wid][half*32 + e + t][kr] = (u16)v[t];
      }
    }
    __syncthreads();   // LDS writes visible before fragment reads

    s16x8 aP = *(const s16x8*)&Pbuf[wid][ln][quad * 8];
    #pragma unroll
    for (int nt = 0; nt < 4; ++nt) {
      s16x8 bV = *(const s16x8*)&Vt[wid][nt*16 + ln][quad * 8];
      o[nt] = __builtin_amdgcn_mfma_f32_16x16x32_bf16(aP, bV, o[nt], 0, 0, 0);
    }
  }
  #pragma unroll
  for (int r = 0; r < 4; ++r) {
    const float inv = 1.0f / li[r];
    const int srow = q0 + quad * 4 + r;
    u16* orow = outp + (size_t)(b * 2048 + srow) * 1024 + h * 64;
    #pragma unroll
    for (int nt = 0; nt < 4; ++nt)
      orow[nt*16 + ln] = f2b(o[nt][r] * inv);
  }
}

// ---------------- launch ----------------
extern "C" void kernel_launch(void* const* d_in, const int* in_sizes, int n_in,
                              void* d_out, int out_size, void* d_ws, size_t ws_size,
                              hipStream_t stream)
{
  (void)in_sizes; (void)n_in; (void)out_size; (void)ws_size;
  const float* x      = (const float*)d_in[0];
  const float* w_qkv  = (const float*)d_in[1];
  const float* b_qkv  = (const float*)d_in[2];
  const float* w_proj = (const float*)d_in[3];
  const float* b_proj = (const float*)d_in[4];
  const float* g1     = (const float*)d_in[5];
  const float* be1    = (const float*)d_in[6];
  const float* g2     = (const float*)d_in[7];
  const float* be2    = (const float*)d_in[8];
  const float* w_fc1  = (const float*)d_in[9];
  const float* b_fc1  = (const float*)d_in[10];
  const float* w_fc2  = (const float*)d_in[11];
  const float* b_fc2  = (const float*)d_in[12];

  // ---- workspace arena, 56 MiB peak (byte ranges; base is u16*) ----
  // hbuf   [ 0, 8)   ln out (reused for ln1 and ln2)
  // wt_qkv [ 8,14)   dead after qkv gemm
  // wt_proj[14,16)   dead after proj gemm
  // qkvb   [16,40)   dead after attn
  // x2f    [16,32)   f32, live proj .. end (aliases dead qkvb)
  // wt_fc2 [32,40)   transposed after attn (aliases dead qkvb tail)
  // wt_fc1 [ 8,16)   transposed after proj (aliases dead wt_qkv/wt_proj)
  // fbuf   [40,56)   fc1 chunk output (16 MiB), reused per chunk
  // attn output (bf16, 8 MiB) lives in d_out; final f32 writes overwrite it.
  u16* base    = (u16*)d_ws;
  u16* hbuf    = base;
  u16* wt_qkv  = base + (size_t) 4194304;  //  8 MiB
  u16* wt_proj = base + (size_t) 7340032;  // 14 MiB
  u16* qkvb    = base + (size_t) 8388608;  // 16 MiB
  float* x2f   = (float*)(base + (size_t)8388608);   // 16 MiB (24 MiB would be qkvb tail)
  u16* wt_fc2  = base + (size_t)16777216;  // 32 MiB
  u16* wt_fc1  = base + (size_t) 4194304;  //  8 MiB (after proj)
  u16* fbuf    = base + (size_t)20971520;  // 40 MiB
  u16* attnb   = (u16*)d_out;
  float* outf  = (float*)d_out;

  dim3 tb(32, 8);

  // stage 1: LN1 + QKV
  ln_k<<<4096, 256, 0, stream>>>(x, g1, be1, hbuf);
  transpose_k<<<dim3(96, 32), tb, 0, stream>>>(w_qkv, wt_qkv, 1024, 3072);
  gemm_bt<0,false,false><<<dim3(24, 32), 256, 0, stream>>>(hbuf, 1024, wt_qkv, 1024,
                                                           b_qkv, nullptr, qkvb, 1024, 3072);
  // stage 2: attention (writes bf16 into d_out)
  attn_k<<<1024, 256, 0, stream>>>(qkvb, attnb);

  // stage 3: proj + residual (f32 trunk), then LN2
  transpose_k<<<dim3(32, 128), tb, 0, stream>>>(w_fc2, wt_fc2, 4096, 1024); // qkvb tail now dead
  transpose_k<<<dim3(32, 32),  tb, 0, stream>>>(w_proj, wt_proj, 1024, 1024);
  gemm_bt<0,true,true><<<dim3(8, 32), 256, 0, stream>>>(attnb, 1024, wt_proj, 1024,
                                                        b_proj, x, x2f, 1024, 1024);
  transpose_k<<<dim3(128, 32), tb, 0, stream>>>(w_fc1, wt_fc1, 1024, 4096);
  ln_k<<<4096, 256, 0, stream>>>(x2f, g2, be2, hbuf);

  // stage 4: MLP in two hidden-chunks of 2048
  // chunk 0: x2f += gelu(h @ W1[:, :2048] + b1) @ W2[:2048, :] + b2
  gemm_bt<1,false,false><<<dim3(16, 32), 256, 0, stream>>>(hbuf, 1024, wt_fc1, 1024,
                                                           b_fc1, nullptr, fbuf, 1024, 2048);
  gemm_bt<0,true,true><<<dim3(8, 32), 256, 0, stream>>>(fbuf, 2048, wt_fc2, 4096,
                                                        b_fc2, x2f, x2f, 2048, 1024);
  // chunk 1: out = x2f + gelu(h @ W1[:, 2048:] + b1') @ W2[2048:, :]
  gemm_bt<1,false,false><<<dim3(16, 32), 256, 0, stream>>>(hbuf, 1024,
                                                           wt_fc1 + (size_t)2048*1024, 1024,
                                                           b_fc1 + 2048, nullptr, fbuf, 1024, 2048);
  gemm_bt<0,true,true><<<dim3(8, 32), 256, 0, stream>>>(fbuf, 2048, wt_fc2 + 2048, 4096,
                                                        nullptr, x2f, outf, 2048, 1024);
}

// Round 4
// 471.990 us; speedup vs baseline: 1.2240x; 1.2240x over previous
//
#include <hip/hip_runtime.h>

typedef unsigned short u16;
typedef short s16x8 __attribute__((ext_vector_type(8)));
typedef short s16x4 __attribute__((ext_vector_type(4)));
typedef float f32x4 __attribute__((ext_vector_type(4)));

__device__ __forceinline__ u16 f2b(float f){
  union { float f; unsigned int i; } v; v.f = f;
  unsigned int r = v.i + 0x7FFFu + ((v.i >> 16) & 1u);
  return (u16)(r >> 16);
}
__device__ __forceinline__ unsigned asu(float f){
  union { float f; unsigned int i; } v; v.f = f; return v.i;
}

// async global->LDS, 16B per lane; lds dest must be wave-uniform base (HW adds lane*16)
__device__ __forceinline__ void gl_lds16(const u16* g, u16* l) {
  __builtin_amdgcn_global_load_lds(
    (const __attribute__((address_space(1))) unsigned int*)(g),
    (__attribute__((address_space(3))) unsigned int*)(l), 16, 0, 0);
}

// ---------------- transpose+convert: in f32 [K][N] -> out bf16 [N][K] ----------------
__global__ __launch_bounds__(256) void transpose_k(const float* __restrict__ in,
                                                   u16* __restrict__ out, int K, int N)
{
  __shared__ u16 tile[32][33];
  const int tx = threadIdx.x, ty = threadIdx.y;
  const int x = blockIdx.x * 32 + tx;
  const int y0 = blockIdx.y * 32;
  #pragma unroll
  for (int j = ty; j < 32; j += 8)
    tile[j][tx] = f2b(in[(size_t)(y0 + j) * N + x]);
  __syncthreads();
  const int x2 = y0 + tx;
  const int y2 = blockIdx.x * 32;
  #pragma unroll
  for (int j = ty; j < 32; j += 8)
    out[(size_t)(y2 + j) * K + x2] = tile[tx][j];
}

// ---------------- layernorm: f32 in, bf16 out; one block per row of 1024 ----------------
__global__ __launch_bounds__(256) void ln_k(const float* __restrict__ xin,
                                            const float* __restrict__ g,
                                            const float* __restrict__ be,
                                            u16* __restrict__ out)
{
  const int row = blockIdx.x, tid = threadIdx.x;
  float4 u = *(const float4*)(xin + (size_t)row * 1024 + tid * 4);
  float v[4] = {u.x, u.y, u.z, u.w};
  float sum = v[0] + v[1] + v[2] + v[3];
  float sq  = v[0]*v[0] + v[1]*v[1] + v[2]*v[2] + v[3]*v[3];
  #pragma unroll
  for (int off = 32; off > 0; off >>= 1) {
    sum += __shfl_down(sum, off, 64);
    sq  += __shfl_down(sq,  off, 64);
  }
  __shared__ float ws1[4], ws2[4];
  const int wid = tid >> 6, lane = tid & 63;
  if (lane == 0) { ws1[wid] = sum; ws2[wid] = sq; }
  __syncthreads();
  const float tot  = ws1[0] + ws1[1] + ws1[2] + ws1[3];
  const float tot2 = ws2[0] + ws2[1] + ws2[2] + ws2[3];
  const float inv = 1.0f / 1024.0f;
  const float mu = tot * inv;
  const float var = tot2 * inv - mu * mu;
  const float rs = rsqrtf(var + 1e-5f);
  float4 gv = *(const float4*)(g  + tid * 4);
  float4 bv = *(const float4*)(be + tid * 4);
  u16 ob[4];
  ob[0] = f2b((v[0] - mu) * rs * gv.x + bv.x);
  ob[1] = f2b((v[1] - mu) * rs * gv.y + bv.y);
  ob[2] = f2b((v[2] - mu) * rs * gv.z + bv.z);
  ob[3] = f2b((v[3] - mu) * rs * gv.w + bv.w);
  uint2 o;
  o.x = (unsigned)ob[0] | ((unsigned)ob[1] << 16);
  o.y = (unsigned)ob[2] | ((unsigned)ob[3] << 16);
  *(uint2*)(out + (size_t)row * 1024 + tid * 4) = o;
}

// ---- GEMM (m97-style): C = act(A[.,K](lda) @ Bt[N,K](ldb)^T + bias) (+f32 res) ----
template<int ACT, bool RES, bool OUTF>
__global__ __launch_bounds__(256) void gemm_bt(const u16* __restrict__ A, int lda,
                                               const u16* __restrict__ Bt, int ldb,
                                               const float* __restrict__ bias,
                                               const float* __restrict__ res,
                                               void* __restrict__ Cout,
                                               int K, int ldc)
{
  __shared__ __align__(16) u16 As[128 * 64];   // unpadded: global_load_lds layout
  __shared__ __align__(16) u16 Bs[128 * 64];
  const int tid = threadIdx.x;
  const int wid = tid >> 6, lane = tid & 63, quad = lane >> 4, ln = lane & 15;
  const int wr = wid >> 1, wc = wid & 1;
  const int m0 = blockIdx.y * 128, n0 = blockIdx.x * 128;

  f32x4 acc[4][4];
  #pragma unroll
  for (int i = 0; i < 4; ++i)
    #pragma unroll
    for (int j = 0; j < 4; ++j)
      #pragma unroll
      for (int r = 0; r < 4; ++r) acc[i][j][r] = 0.f;

  const int srow = wid * 32 + (lane >> 3);   // + i*8
  const int scol = (lane & 7) * 8;

  for (int k0 = 0; k0 < K; k0 += 64) {
    __syncthreads();
    #pragma unroll
    for (int i = 0; i < 4; ++i) {
      const int row = srow + i * 8;
      gl_lds16(&A [(size_t)(m0 + row) * lda + k0 + scol], &As[wid * 2048 + i * 512]);
      gl_lds16(&Bt[(size_t)(n0 + row) * ldb + k0 + scol], &Bs[wid * 2048 + i * 512]);
    }
    __syncthreads();
    #pragma unroll
    for (int ks = 0; ks < 2; ++ks) {
      s16x8 af[4], bfr[4];
      #pragma unroll
      for (int i = 0; i < 4; ++i) af[i]  = *(const s16x8*)&As[(wr*64 + i*16 + ln)*64 + ks*32 + quad*8];
      #pragma unroll
      for (int j = 0; j < 4; ++j) bfr[j] = *(const s16x8*)&Bs[(wc*64 + j*16 + ln)*64 + ks*32 + quad*8];
      #pragma unroll
      for (int i = 0; i < 4; ++i)
        #pragma unroll
        for (int j = 0; j < 4; ++j)
          acc[i][j] = __builtin_amdgcn_mfma_f32_16x16x32_bf16(af[i], bfr[j], acc[i][j], 0, 0, 0);
    }
  }

  float bv[4];
  #pragma unroll
  for (int j = 0; j < 4; ++j) bv[j] = bias ? bias[n0 + wc*64 + j*16 + ln] : 0.f;

  #pragma unroll
  for (int i = 0; i < 4; ++i) {
    #pragma unroll
    for (int r = 0; r < 4; ++r) {
      const int row = m0 + wr*64 + i*16 + quad*4 + r;
      #pragma unroll
      for (int j = 0; j < 4; ++j) {
        const int col = n0 + wc*64 + j*16 + ln;
        const size_t idx = (size_t)row * ldc + col;
        float v = acc[i][j][r] + bv[j];
        if (RES) v += res[idx];
        if (ACT == 1) v = 0.5f * v * (1.f + erff(v * 0.70710678118f));
        if (OUTF) ((float*)Cout)[idx] = v;
        else      ((u16*)Cout)[idx] = f2b(v);
      }
    }
  }
}

// ---------------- flash attention v2: S^T trick, cooperative staging, causal pairing ----------------
// grid: 512 blocks = (pair j in 0..15) + 16*(bh in 0..31). Block does q-blocks j and 31-j.
// Per wave: 16 q-rows (q = qb*64 + wid*16 + ln). Key tiles of 64.
__global__ __launch_bounds__(256) void attn_k(const u16* __restrict__ qkv,
                                              u16* __restrict__ outp)
{
  constexpr int LDK = 72;  // stride: 144B rows, 16B-aligned, 2-way-max conflicts
  __shared__ __align__(16) u16 Kt[64 * LDK];   // Kt[key][dim]
  __shared__ __align__(16) u16 Vt[64 * LDK];   // Vt[dim][key]
  const int tid = threadIdx.x, wid = tid >> 6, lane = tid & 63;
  const int quad = lane >> 4, ln = lane & 15;
  const int blk = blockIdx.x, j = blk & 15, bh = blk >> 4, b = bh >> 4, h = bh & 15;
  const u16* base = qkv + (size_t)b * 2048 * 3072;
  const float scale = 0.125f;   // 1/sqrt(64)

  const int tkr = tid >> 2, tkc = (tid & 3) * 16;   // K staging: row, dim-start

  for (int qi = 0; qi < 2; ++qi) {
    const int qb = qi ? (31 - j) : j;
    const int qw0 = qb * 64 + wid * 16;
    const int qmax = qw0 + 15;
    const int qln  = qw0 + ln;          // this lane's q row

    s16x8 aQ0, aQ1;
    {
      const u16* qrow = base + (size_t)qln * 3072 + h * 64 + quad * 8;
      aQ0 = *(const s16x8*)(qrow);
      aQ1 = *(const s16x8*)(qrow + 32);
    }
    f32x4 o[4];
    float mi = -1e30f, li = 0.f;
    #pragma unroll
    for (int dt = 0; dt < 4; ++dt)
      #pragma unroll
      for (int r = 0; r < 4; ++r) o[dt][r] = 0.f;

    const int nkt = qb + 1;
    for (int kt = 0; kt < nkt; ++kt) {
      const int kb = kt * 64;
      __syncthreads();   // previous tile's LDS reads done
      {  // stage K tile [64 keys][64 dims], vector writes
        const u16* krow = base + (size_t)(kb + tkr) * 3072 + 1024 + h * 64 + tkc;
        *(s16x8*)&Kt[tkr * LDK + tkc]     = *(const s16x8*)(krow);
        *(s16x8*)&Kt[tkr * LDK + tkc + 8] = *(const s16x8*)(krow + 8);
      }
      {  // stage V transposed: wave wid handles dim-quarter wid, lane = key row
        const u16* vrow = base + (size_t)(kb + lane) * 3072 + 2048 + h * 64 + wid * 16;
        s16x8 va = *(const s16x8*)(vrow);
        s16x8 vb = *(const s16x8*)(vrow + 8);
        #pragma unroll
        for (int e = 0; e < 8; ++e) {
          Vt[(wid * 16 + e) * LDK + lane]     = (u16)va[e];
          Vt[(wid * 16 + 8 + e) * LDK + lane] = (u16)vb[e];
        }
      }
      __syncthreads();

      // active 16-key sub-tiles for this wave (rest fully masked)
      const int mtn = min(4, ((qmax - kb) >> 4) + 1);

      // S^T = K·Q^T : A = K rows (m=key), B = Q rows (n=q)
      f32x4 s[4];
      #pragma unroll
      for (int mt = 0; mt < 4; ++mt) if (mt < mtn) {
        f32x4 a;
        #pragma unroll
        for (int r = 0; r < 4; ++r) a[r] = 0.f;
        s16x8 k0 = *(const s16x8*)&Kt[(mt*16 + ln) * LDK + quad * 8];
        s16x8 k1 = *(const s16x8*)&Kt[(mt*16 + ln) * LDK + 32 + quad * 8];
        a = __builtin_amdgcn_mfma_f32_16x16x32_bf16(k0, aQ0, a, 0, 0, 0);
        a = __builtin_amdgcn_mfma_f32_16x16x32_bf16(k1, aQ1, a, 0, 0, 0);
        s[mt] = a;   // s[mt][r] = S^T[kb+mt*16+quad*4+r][qln]  (raw score)
      }

      // mask + running max (per-lane scalar state; keys live on quad*4+r)
      float mnew = mi;
      #pragma unroll
      for (int mt = 0; mt < 4; ++mt) if (mt < mtn) {
        #pragma unroll
        for (int r = 0; r < 4; ++r) {
          const int key = kb + mt*16 + quad*4 + r;
          float v = (key <= qln) ? s[mt][r] : -1e30f;
          s[mt][r] = v;
          mnew = fmaxf(mnew, v);
        }
      }
      mnew = fmaxf(mnew, __shfl_xor(mnew, 16, 64));
      mnew = fmaxf(mnew, __shfl_xor(mnew, 32, 64));
      const float alpha = __expf((mi - mnew) * scale);
      float rsum = 0.f;
      #pragma unroll
      for (int mt = 0; mt < 4; ++mt) if (mt < mtn) {
        #pragma unroll
        for (int r = 0; r < 4; ++r) {
          float p = __expf((s[mt][r] - mnew) * scale);
          s[mt][r] = p;
          rsum += p;
        }
      }
      rsum += __shfl_xor(rsum, 16, 64);
      rsum += __shfl_xor(rsum, 32, 64);
      li = li * alpha + rsum;
      mi = mnew;
      #pragma unroll
      for (int dt = 0; dt < 4; ++dt)
        #pragma unroll
        for (int r = 0; r < 4; ++r) o[dt][r] *= alpha;

      // PV: O^T += V^T · P^T. P^T C-layout == B-operand of 16x16x16 (k=quad*4+r, n=ln).
      #pragma unroll
      for (int mt = 0; mt < 4; ++mt) if (mt < mtn) {
        const unsigned lo = ((asu(s[mt][0]) + 0x8000u) >> 16) | ((asu(s[mt][1]) + 0x8000u) & 0xFFFF0000u);
        const unsigned hi = ((asu(s[mt][2]) + 0x8000u) >> 16) | ((asu(s[mt][3]) + 0x8000u) & 0xFFFF0000u);
        union { unsigned u[2]; s16x4 v; } bp; bp.u[0] = lo; bp.u[1] = hi;
        #pragma unroll
        for (int dt = 0; dt < 4; ++dt) {
          s16x4 aV = *(const s16x4*)&Vt[(dt*16 + ln) * LDK + mt*16 + quad*4];
          o[dt] = __builtin_amdgcn_mfma_f32_16x16x16bf16_1k(aV, bp.v, o[dt], 0, 0, 0);
        }
      }
    } // kt

    const float inv = 1.0f / li;
    u16* orow = outp + (size_t)(b * 2048 + qln) * 1024 + h * 64;
    #pragma unroll
    for (int dt = 0; dt < 4; ++dt)
      #pragma unroll
      for (int r = 0; r < 4; ++r)
        orow[dt*16 + quad*4 + r] = f2b(o[dt][r] * inv);
  } // qi
}

// ---------------- launch ----------------
extern "C" void kernel_launch(void* const* d_in, const int* in_sizes, int n_in,
                              void* d_out, int out_size, void* d_ws, size_t ws_size,
                              hipStream_t stream)
{
  (void)in_sizes; (void)n_in; (void)out_size; (void)ws_size;
  const float* x      = (const float*)d_in[0];
  const float* w_qkv  = (const float*)d_in[1];
  const float* b_qkv  = (const float*)d_in[2];
  const float* w_proj = (const float*)d_in[3];
  const float* b_proj = (const float*)d_in[4];
  const float* g1     = (const float*)d_in[5];
  const float* be1    = (const float*)d_in[6];
  const float* g2     = (const float*)d_in[7];
  const float* be2    = (const float*)d_in[8];
  const float* w_fc1  = (const float*)d_in[9];
  const float* b_fc1  = (const float*)d_in[10];
  const float* w_fc2  = (const float*)d_in[11];
  const float* b_fc2  = (const float*)d_in[12];

  // ---- workspace arena, 56 MiB peak (same proven layout as R3) ----
  u16* base    = (u16*)d_ws;
  u16* hbuf    = base;
  u16* wt_qkv  = base + (size_t) 4194304;  //  8 MiB
  u16* wt_proj = base + (size_t) 7340032;  // 14 MiB
  u16* qkvb    = base + (size_t) 8388608;  // 16 MiB
  float* x2f   = (float*)(base + (size_t)8388608);   // 16..32 MiB (aliases dead qkvb head)
  u16* wt_fc2  = base + (size_t)16777216;  // 32 MiB
  u16* wt_fc1  = base + (size_t) 4194304;  //  8 MiB (after proj)
  u16* fbuf    = base + (size_t)20971520;  // 40 MiB
  u16* attnb   = (u16*)d_out;
  float* outf  = (float*)d_out;

  dim3 tb(32, 8);

  // stage 1: LN1 + QKV
  ln_k<<<4096, 256, 0, stream>>>(x, g1, be1, hbuf);
  transpose_k<<<dim3(96, 32), tb, 0, stream>>>(w_qkv, wt_qkv, 1024, 3072);
  gemm_bt<0,false,false><<<dim3(24, 32), 256, 0, stream>>>(hbuf, 1024, wt_qkv, 1024,
                                                           b_qkv, nullptr, qkvb, 1024, 3072);
  // stage 2: attention (writes bf16 into d_out)
  attn_k<<<512, 256, 0, stream>>>(qkvb, attnb);

  // stage 3: proj + residual (f32 trunk), then LN2
  transpose_k<<<dim3(32, 128), tb, 0, stream>>>(w_fc2, wt_fc2, 4096, 1024); // qkvb tail now dead
  transpose_k<<<dim3(32, 32),  tb, 0, stream>>>(w_proj, wt_proj, 1024, 1024);
  gemm_bt<0,true,true><<<dim3(8, 32), 256, 0, stream>>>(attnb, 1024, wt_proj, 1024,
                                                        b_proj, x, x2f, 1024, 1024);
  transpose_k<<<dim3(128, 32), tb, 0, stream>>>(w_fc1, wt_fc1, 1024, 4096);
  ln_k<<<4096, 256, 0, stream>>>(x2f, g2, be2, hbuf);

  // stage 4: MLP in two hidden-chunks of 2048
  gemm_bt<1,false,false><<<dim3(16, 32), 256, 0, stream>>>(hbuf, 1024, wt_fc1, 1024,
                                                           b_fc1, nullptr, fbuf, 1024, 2048);
  gemm_bt<0,true,true><<<dim3(8, 32), 256, 0, stream>>>(fbuf, 2048, wt_fc2, 4096,
                                                        b_fc2, x2f, x2f, 2048, 1024);
  gemm_bt<1,false,false><<<dim3(16, 32), 256, 0, stream>>>(hbuf, 1024,
                                                           wt_fc1 + (size_t)2048*1024, 1024,
                                                           b_fc1 + 2048, nullptr, fbuf, 1024, 2048);
  gemm_bt<0,true,true><<<dim3(8, 32), 256, 0, stream>>>(fbuf, 2048, wt_fc2 + 2048, 4096,
                                                        nullptr, x2f, outf, 2048, 1024);
}

// Round 5
// 436.078 us; speedup vs baseline: 1.3248x; 1.0824x over previous
//
#include <hip/hip_runtime.h>

typedef unsigned short u16;
typedef unsigned int u32;
typedef short s16x8 __attribute__((ext_vector_type(8)));
typedef short s16x4 __attribute__((ext_vector_type(4)));
typedef float f32x4 __attribute__((ext_vector_type(4)));

__device__ __forceinline__ u16 f2b(float f){
  union { float f; unsigned int i; } v; v.f = f;
  unsigned int r = v.i + 0x7FFFu + ((v.i >> 16) & 1u);
  return (u16)(r >> 16);
}
__device__ __forceinline__ u32 asu(float f){
  union { float f; unsigned int i; } v; v.f = f; return v.i;
}
// pack two f32 -> (bf16(a) | bf16(b)<<16) via v_perm, round-half-up
__device__ __forceinline__ u32 pkbf(float a, float b){
  return __builtin_amdgcn_perm(asu(b) + 0x8000u, asu(a) + 0x8000u, 0x07060302u);
}

// async global->LDS, 16B per lane; lds dest wave-uniform base (HW adds lane*16)
__device__ __forceinline__ void gl_lds16(const u16* g, u16* l) {
  __builtin_amdgcn_global_load_lds(
    (const __attribute__((address_space(1))) unsigned int*)(g),
    (__attribute__((address_space(3))) unsigned int*)(l), 16, 0, 0);
}

// ---------------- transpose+convert: in f32 [K][N] -> out bf16 [N][K] ----------------
__global__ __launch_bounds__(256) void transpose_k(const float* __restrict__ in,
                                                   u16* __restrict__ out, int K, int N)
{
  __shared__ u16 tile[32][33];
  const int tx = threadIdx.x, ty = threadIdx.y;
  const int x = blockIdx.x * 32 + tx;
  const int y0 = blockIdx.y * 32;
  #pragma unroll
  for (int j = ty; j < 32; j += 8)
    tile[j][tx] = f2b(in[(size_t)(y0 + j) * N + x]);
  __syncthreads();
  const int x2 = y0 + tx;
  const int y2 = blockIdx.x * 32;
  #pragma unroll
  for (int j = ty; j < 32; j += 8)
    out[(size_t)(y2 + j) * K + x2] = tile[tx][j];
}

// ---------------- layernorm: f32 in, bf16 out; one block per row of 1024 ----------------
__global__ __launch_bounds__(256) void ln_k(const float* __restrict__ xin,
                                            const float* __restrict__ g,
                                            const float* __restrict__ be,
                                            u16* __restrict__ out)
{
  const int row = blockIdx.x, tid = threadIdx.x;
  float4 u = *(const float4*)(xin + (size_t)row * 1024 + tid * 4);
  float v[4] = {u.x, u.y, u.z, u.w};
  float sum = v[0] + v[1] + v[2] + v[3];
  float sq  = v[0]*v[0] + v[1]*v[1] + v[2]*v[2] + v[3]*v[3];
  #pragma unroll
  for (int off = 32; off > 0; off >>= 1) {
    sum += __shfl_down(sum, off, 64);
    sq  += __shfl_down(sq,  off, 64);
  }
  __shared__ float ws1[4], ws2[4];
  const int wid = tid >> 6, lane = tid & 63;
  if (lane == 0) { ws1[wid] = sum; ws2[wid] = sq; }
  __syncthreads();
  const float tot  = ws1[0] + ws1[1] + ws1[2] + ws1[3];
  const float tot2 = ws2[0] + ws2[1] + ws2[2] + ws2[3];
  const float inv = 1.0f / 1024.0f;
  const float mu = tot * inv;
  const float var = tot2 * inv - mu * mu;
  const float rs = rsqrtf(var + 1e-5f);
  float4 gv = *(const float4*)(g  + tid * 4);
  float4 bv = *(const float4*)(be + tid * 4);
  u16 ob[4];
  ob[0] = f2b((v[0] - mu) * rs * gv.x + bv.x);
  ob[1] = f2b((v[1] - mu) * rs * gv.y + bv.y);
  ob[2] = f2b((v[2] - mu) * rs * gv.z + bv.z);
  ob[3] = f2b((v[3] - mu) * rs * gv.w + bv.w);
  uint2 o;
  o.x = (unsigned)ob[0] | ((unsigned)ob[1] << 16);
  o.y = (unsigned)ob[2] | ((unsigned)ob[3] << 16);
  *(uint2*)(out + (size_t)row * 1024 + tid * 4) = o;
}

// ---- shared GEMM epilogue ----
template<int ACT, bool RES, bool OUTF>
__device__ __forceinline__ void gemm_epilogue(f32x4 (&acc)[4][4],
    const float* bias, const float* res, void* Cout,
    int m0, int n0, int ldc, int wr, int wc, int quad, int ln)
{
  float bv[4];
  #pragma unroll
  for (int j = 0; j < 4; ++j) bv[j] = bias ? bias[n0 + wc*64 + j*16 + ln] : 0.f;
  #pragma unroll
  for (int i = 0; i < 4; ++i) {
    #pragma unroll
    for (int r = 0; r < 4; ++r) {
      const int row = m0 + wr*64 + i*16 + quad*4 + r;
      #pragma unroll
      for (int j = 0; j < 4; ++j) {
        const int col = n0 + wc*64 + j*16 + ln;
        const size_t idx = (size_t)row * ldc + col;
        float v = acc[i][j][r] + bv[j];
        if (RES) v += res[idx];
        if (ACT == 1) v = 0.5f * v * (1.f + erff(v * 0.70710678118f));
        if (OUTF) ((float*)Cout)[idx] = v;
        else      ((u16*)Cout)[idx] = f2b(v);
      }
    }
  }
}

// ---- GEMM A (m97-style gl_lds): for grids with >=2 blocks/CU ----
template<int ACT, bool RES, bool OUTF>
__global__ __launch_bounds__(256) void gemm_lds(const u16* __restrict__ A, int lda,
                                                const u16* __restrict__ Bt, int ldb,
                                                const float* __restrict__ bias,
                                                const float* __restrict__ res,
                                                void* __restrict__ Cout,
                                                int K, int ldc)
{
  __shared__ __align__(16) u16 As[128 * 64];
  __shared__ __align__(16) u16 Bs[128 * 64];
  const int tid = threadIdx.x;
  const int wid = tid >> 6, lane = tid & 63, quad = lane >> 4, ln = lane & 15;
  const int wr = wid >> 1, wc = wid & 1;
  const int m0 = blockIdx.y * 128, n0 = blockIdx.x * 128;

  f32x4 acc[4][4];
  #pragma unroll
  for (int i = 0; i < 4; ++i)
    #pragma unroll
    for (int j = 0; j < 4; ++j)
      #pragma unroll
      for (int r = 0; r < 4; ++r) acc[i][j][r] = 0.f;

  const int srow = wid * 32 + (lane >> 3);
  const int scol = (lane & 7) * 8;

  for (int k0 = 0; k0 < K; k0 += 64) {
    __syncthreads();
    #pragma unroll
    for (int i = 0; i < 4; ++i) {
      const int row = srow + i * 8;
      gl_lds16(&A [(size_t)(m0 + row) * lda + k0 + scol], &As[wid * 2048 + i * 512]);
      gl_lds16(&Bt[(size_t)(n0 + row) * ldb + k0 + scol], &Bs[wid * 2048 + i * 512]);
    }
    __syncthreads();
    #pragma unroll
    for (int ks = 0; ks < 2; ++ks) {
      s16x8 af[4], bfr[4];
      #pragma unroll
      for (int i = 0; i < 4; ++i) af[i]  = *(const s16x8*)&As[(wr*64 + i*16 + ln)*64 + ks*32 + quad*8];
      #pragma unroll
      for (int j = 0; j < 4; ++j) bfr[j] = *(const s16x8*)&Bs[(wc*64 + j*16 + ln)*64 + ks*32 + quad*8];
      #pragma unroll
      for (int i = 0; i < 4; ++i)
        #pragma unroll
        for (int j = 0; j < 4; ++j)
          acc[i][j] = __builtin_amdgcn_mfma_f32_16x16x32_bf16(af[i], bfr[j], acc[i][j], 0, 0, 0);
    }
  }
  gemm_epilogue<ACT,RES,OUTF>(acc, bias, res, Cout, m0, n0, ldc, wr, wc, quad, ln);
}

// ---- GEMM B (register double-buffer prefetch): loads stay in flight across the
// barrier -> tolerates 1 block/CU. For small grids (proj, fc2). ----
template<int ACT, bool RES, bool OUTF>
__global__ __launch_bounds__(256) void gemm_pf(const u16* __restrict__ A, int lda,
                                               const u16* __restrict__ Bt, int ldb,
                                               const float* __restrict__ bias,
                                               const float* __restrict__ res,
                                               void* __restrict__ Cout,
                                               int K, int ldc)
{
  __shared__ __align__(16) u16 As[128 * 64];
  __shared__ __align__(16) u16 Bs[128 * 64];
  const int tid = threadIdx.x;
  const int wid = tid >> 6, lane = tid & 63, quad = lane >> 4, ln = lane & 15;
  const int wr = wid >> 1, wc = wid & 1;
  const int m0 = blockIdx.y * 128, n0 = blockIdx.x * 128;

  f32x4 acc[4][4];
  #pragma unroll
  for (int i = 0; i < 4; ++i)
    #pragma unroll
    for (int j = 0; j < 4; ++j)
      #pragma unroll
      for (int r = 0; r < 4; ++r) acc[i][j][r] = 0.f;

  const int lr = tid >> 1;             // 0..127
  const int lc = (tid & 1) * 32;       // 0 or 32

  s16x8 ra[4], rb[4];
  const u16* Abase = &A [(size_t)(m0 + lr) * lda + lc];
  const u16* Bbase = &Bt[(size_t)(n0 + lr) * ldb + lc];
  #pragma unroll
  for (int i = 0; i < 4; ++i) { ra[i] = *(const s16x8*)(Abase + i*8); rb[i] = *(const s16x8*)(Bbase + i*8); }

  for (int k0 = 0; k0 < K; k0 += 64) {
    #pragma unroll
    for (int i = 0; i < 4; ++i) {
      *(s16x8*)&As[lr * 64 + lc + i*8] = ra[i];
      *(s16x8*)&Bs[lr * 64 + lc + i*8] = rb[i];
    }
    __syncthreads();
    if (k0 + 64 < K) {
      const u16* An = Abase + k0 + 64;
      const u16* Bn = Bbase + k0 + 64;
      #pragma unroll
      for (int i = 0; i < 4; ++i) { ra[i] = *(const s16x8*)(An + i*8); rb[i] = *(const s16x8*)(Bn + i*8); }
    }
    #pragma unroll
    for (int ks = 0; ks < 2; ++ks) {
      s16x8 af[4], bfr[4];
      #pragma unroll
      for (int i = 0; i < 4; ++i) af[i]  = *(const s16x8*)&As[(wr*64 + i*16 + ln)*64 + ks*32 + quad*8];
      #pragma unroll
      for (int j = 0; j < 4; ++j) bfr[j] = *(const s16x8*)&Bs[(wc*64 + j*16 + ln)*64 + ks*32 + quad*8];
      #pragma unroll
      for (int i = 0; i < 4; ++i)
        #pragma unroll
        for (int j = 0; j < 4; ++j)
          acc[i][j] = __builtin_amdgcn_mfma_f32_16x16x32_bf16(af[i], bfr[j], acc[i][j], 0, 0, 0);
    }
    __syncthreads();
  }
  gemm_epilogue<ACT,RES,OUTF>(acc, bias, res, Cout, m0, n0, ldc, wr, wc, quad, ln);
}

// ---------------- flash attention v3: no online softmax (bounded scores), ----------------
// no shuffles in K-loop, mask only on the diagonal tile.
// grid: 1024 blocks, qb = 31 - (blk>>5) (long blocks first), bh = blk & 31.
__global__ __launch_bounds__(256) void attn_k(const u16* __restrict__ qkv,
                                              u16* __restrict__ outp)
{
  constexpr int LDK = 72;
  __shared__ __align__(16) u16 Kt[64 * LDK];   // Kt[key][dim]
  __shared__ __align__(16) u16 Vt[64 * LDK];   // Vt[dim][key]
  const int tid = threadIdx.x, wid = tid >> 6, lane = tid & 63;
  const int quad = lane >> 4, ln = lane & 15;
  const int qb = 31 - (blockIdx.x >> 5);
  const int bh = blockIdx.x & 31, b = bh >> 4, h = bh & 15;
  const u16* base = qkv + (size_t)b * 2048 * 3072;
  const float C = 0.18033688f;   // 0.125 * log2(e)

  const int tkr = tid >> 2, tkc = (tid & 3) * 16;
  const int qln = qb * 64 + wid * 16 + ln;

  s16x8 aQ0, aQ1;
  {
    const u16* qrow = base + (size_t)qln * 3072 + h * 64 + quad * 8;
    aQ0 = *(const s16x8*)(qrow);
    aQ1 = *(const s16x8*)(qrow + 32);
  }
  f32x4 o[4];
  float lsum = 0.f;
  #pragma unroll
  for (int dt = 0; dt < 4; ++dt)
    #pragma unroll
    for (int r = 0; r < 4; ++r) o[dt][r] = 0.f;

  // ---- full tiles: kt = 0 .. qb-1 (no masking anywhere) ----
  for (int kt = 0; kt < qb; ++kt) {
    const int kb = kt * 64;
    __syncthreads();
    {
      const u16* krow = base + (size_t)(kb + tkr) * 3072 + 1024 + h * 64 + tkc;
      *(s16x8*)&Kt[tkr * LDK + tkc]     = *(const s16x8*)(krow);
      *(s16x8*)&Kt[tkr * LDK + tkc + 8] = *(const s16x8*)(krow + 8);
      const u16* vrow = base + (size_t)(kb + lane) * 3072 + 2048 + h * 64 + wid * 16;
      s16x8 va = *(const s16x8*)(vrow);
      s16x8 vb = *(const s16x8*)(vrow + 8);
      #pragma unroll
      for (int e = 0; e < 8; ++e) {
        Vt[(wid * 16 + e) * LDK + lane]     = (u16)va[e];
        Vt[(wid * 16 + 8 + e) * LDK + lane] = (u16)vb[e];
      }
    }
    __syncthreads();

    #pragma unroll
    for (int mt = 0; mt < 4; ++mt) {
      f32x4 s;
      #pragma unroll
      for (int r = 0; r < 4; ++r) s[r] = 0.f;
      s16x8 k0 = *(const s16x8*)&Kt[(mt*16 + ln) * LDK + quad * 8];
      s16x8 k1 = *(const s16x8*)&Kt[(mt*16 + ln) * LDK + 32 + quad * 8];
      s = __builtin_amdgcn_mfma_f32_16x16x32_bf16(k0, aQ0, s, 0, 0, 0);
      s = __builtin_amdgcn_mfma_f32_16x16x32_bf16(k1, aQ1, s, 0, 0, 0);
      float p0 = exp2f(s[0] * C), p1 = exp2f(s[1] * C);
      float p2 = exp2f(s[2] * C), p3 = exp2f(s[3] * C);
      lsum += (p0 + p1) + (p2 + p3);
      union { u32 u[2]; s16x4 v; } bp;
      bp.u[0] = pkbf(p0, p1); bp.u[1] = pkbf(p2, p3);
      #pragma unroll
      for (int dt = 0; dt < 4; ++dt) {
        s16x4 aV = *(const s16x4*)&Vt[(dt*16 + ln) * LDK + mt*16 + quad*4];
        o[dt] = __builtin_amdgcn_mfma_f32_16x16x16bf16_1k(aV, bp.v, o[dt], 0, 0, 0);
      }
    }
  }

  // ---- diagonal tile kt == qb ----
  {
    const int kb = qb * 64;
    __syncthreads();
    {
      const u16* krow = base + (size_t)(kb + tkr) * 3072 + 1024 + h * 64 + tkc;
      *(s16x8*)&Kt[tkr * LDK + tkc]     = *(const s16x8*)(krow);
      *(s16x8*)&Kt[tkr * LDK + tkc + 8] = *(const s16x8*)(krow + 8);
      const u16* vrow = base + (size_t)(kb + lane) * 3072 + 2048 + h * 64 + wid * 16;
      s16x8 va = *(const s16x8*)(vrow);
      s16x8 vb = *(const s16x8*)(vrow + 8);
      #pragma unroll
      for (int e = 0; e < 8; ++e) {
        Vt[(wid * 16 + e) * LDK + lane]     = (u16)va[e];
        Vt[(wid * 16 + 8 + e) * LDK + lane] = (u16)vb[e];
      }
    }
    __syncthreads();

    #pragma unroll
    for (int mt = 0; mt < 4; ++mt) {
      if (mt <= wid) {           // wave-uniform branch
        f32x4 s;
        #pragma unroll
        for (int r = 0; r < 4; ++r) s[r] = 0.f;
        s16x8 k0 = *(const s16x8*)&Kt[(mt*16 + ln) * LDK + quad * 8];
        s16x8 k1 = *(const s16x8*)&Kt[(mt*16 + ln) * LDK + 32 + quad * 8];
        s = __builtin_amdgcn_mfma_f32_16x16x32_bf16(k0, aQ0, s, 0, 0, 0);
        s = __builtin_amdgcn_mfma_f32_16x16x32_bf16(k1, aQ1, s, 0, 0, 0);
        float p[4];
        #pragma unroll
        for (int r = 0; r < 4; ++r) {
          p[r] = exp2f(s[r] * C);
          if (mt == wid && (quad*4 + r) > ln) p[r] = 0.f;   // causal mask, lane-local
        }
        lsum += (p[0] + p[1]) + (p[2] + p[3]);
        union { u32 u[2]; s16x4 v; } bp;
        bp.u[0] = pkbf(p[0], p[1]); bp.u[1] = pkbf(p[2], p[3]);
        #pragma unroll
        for (int dt = 0; dt < 4; ++dt) {
          s16x4 aV = *(const s16x4*)&Vt[(dt*16 + ln) * LDK + mt*16 + quad*4];
          o[dt] = __builtin_amdgcn_mfma_f32_16x16x16bf16_1k(aV, bp.v, o[dt], 0, 0, 0);
        }
      }
    }
  }

  // one cross-lane reduction per q-block (q on lane index ln; partials on quad)
  lsum += __shfl_xor(lsum, 16, 64);
  lsum += __shfl_xor(lsum, 32, 64);
  const float inv = 1.0f / lsum;

  u16* orow = outp + (size_t)(b * 2048 + qln) * 1024 + h * 64;
  #pragma unroll
  for (int dt = 0; dt < 4; ++dt) {
    uint2 w;
    w.x = pkbf(o[dt][0] * inv, o[dt][1] * inv);
    w.y = pkbf(o[dt][2] * inv, o[dt][3] * inv);
    *(uint2*)(orow + dt*16 + quad*4) = w;
  }
}

// ---------------- launch ----------------
extern "C" void kernel_launch(void* const* d_in, const int* in_sizes, int n_in,
                              void* d_out, int out_size, void* d_ws, size_t ws_size,
                              hipStream_t stream)
{
  (void)in_sizes; (void)n_in; (void)out_size;
  const float* x      = (const float*)d_in[0];
  const float* w_qkv  = (const float*)d_in[1];
  const float* b_qkv  = (const float*)d_in[2];
  const float* w_proj = (const float*)d_in[3];
  const float* b_proj = (const float*)d_in[4];
  const float* g1     = (const float*)d_in[5];
  const float* be1    = (const float*)d_in[6];
  const float* g2     = (const float*)d_in[7];
  const float* be2    = (const float*)d_in[8];
  const float* w_fc1  = (const float*)d_in[9];
  const float* b_fc1  = (const float*)d_in[10];
  const float* w_fc2  = (const float*)d_in[11];
  const float* b_fc2  = (const float*)d_in[12];

  u16* base    = (u16*)d_ws;
  u16* hbuf    = base;                               //  [0, 8) MiB
  u16* wt_qkv  = base + (size_t) 4194304;            //  [8,14)
  u16* wt_proj = base + (size_t) 7340032;            //  [14,16)
  u16* qkvb    = base + (size_t) 8388608;            //  [16,40)  dead after attn
  float* x2f   = (float*)(base + (size_t)8388608);   //  [16,32)  after attn
  u16* wt_fc2  = base + (size_t)16777216;            //  [32,40)  after attn
  u16* wt_fc1  = base + (size_t) 4194304;            //  [8,16)   after proj
  u16* fbuf    = base + (size_t)20971520;            //  [40, 40+16/32)
  u16* attnb   = (u16*)d_out;
  float* outf  = (float*)d_out;

  dim3 tb(32, 8);

  // stage 1: LN1 + QKV
  ln_k<<<4096, 256, 0, stream>>>(x, g1, be1, hbuf);
  transpose_k<<<dim3(96, 32), tb, 0, stream>>>(w_qkv, wt_qkv, 1024, 3072);
  gemm_lds<0,false,false><<<dim3(24, 32), 256, 0, stream>>>(hbuf, 1024, wt_qkv, 1024,
                                                            b_qkv, nullptr, qkvb, 1024, 3072);
  // stage 2: attention (bf16 out into d_out)
  attn_k<<<1024, 256, 0, stream>>>(qkvb, attnb);

  // stage 3: proj + residual (f32 trunk), then LN2
  transpose_k<<<dim3(32, 128), tb, 0, stream>>>(w_fc2, wt_fc2, 4096, 1024);
  transpose_k<<<dim3(32, 32),  tb, 0, stream>>>(w_proj, wt_proj, 1024, 1024);
  gemm_pf<0,true,true><<<dim3(8, 32), 256, 0, stream>>>(attnb, 1024, wt_proj, 1024,
                                                        b_proj, x, x2f, 1024, 1024);
  transpose_k<<<dim3(128, 32), tb, 0, stream>>>(w_fc1, wt_fc1, 1024, 4096);
  ln_k<<<4096, 256, 0, stream>>>(x2f, g2, be2, hbuf);

  if (ws_size >= (size_t)72 * 1024 * 1024) {
    // merged MLP: fbuf = [4096][4096] bf16 (32 MiB), fc1 1024 blocks, fc2 K=4096
    gemm_lds<1,false,false><<<dim3(32, 32), 256, 0, stream>>>(hbuf, 1024, wt_fc1, 1024,
                                                              b_fc1, nullptr, fbuf, 1024, 4096);
    gemm_pf<0,true,true><<<dim3(8, 32), 256, 0, stream>>>(fbuf, 4096, wt_fc2, 4096,
                                                          b_fc2, x2f, outf, 4096, 1024);
  } else {
    // chunked MLP (56 MiB path, proven)
    gemm_lds<1,false,false><<<dim3(16, 32), 256, 0, stream>>>(hbuf, 1024, wt_fc1, 1024,
                                                              b_fc1, nullptr, fbuf, 1024, 2048);
    gemm_pf<0,true,true><<<dim3(8, 32), 256, 0, stream>>>(fbuf, 2048, wt_fc2, 4096,
                                                          b_fc2, x2f, x2f, 2048, 1024);
    gemm_lds<1,false,false><<<dim3(16, 32), 256, 0, stream>>>(hbuf, 1024,
                                                              wt_fc1 + (size_t)2048*1024, 1024,
                                                              b_fc1 + 2048, nullptr, fbuf, 1024, 2048);
    gemm_pf<0,true,true><<<dim3(8, 32), 256, 0, stream>>>(fbuf, 2048, wt_fc2 + 2048, 4096,
                                                          nullptr, x2f, outf, 2048, 1024);
  }
}

// Round 6
// 423.106 us; speedup vs baseline: 1.3654x; 1.0307x over previous
//
#include <hip/hip_runtime.h>

typedef unsigned short u16;
typedef unsigned int u32;
typedef short s16x8 __attribute__((ext_vector_type(8)));
typedef short s16x4 __attribute__((ext_vector_type(4)));
typedef float f32x4 __attribute__((ext_vector_type(4)));

__device__ __forceinline__ u16 f2b(float f){
  union { float f; unsigned int i; } v; v.f = f;
  unsigned int r = v.i + 0x7FFFu + ((v.i >> 16) & 1u);
  return (u16)(r >> 16);
}
__device__ __forceinline__ u32 asu(float f){
  union { float f; unsigned int i; } v; v.f = f; return v.i;
}
// pack two f32 -> (bf16(a) | bf16(b)<<16) via v_perm, round-half-up
__device__ __forceinline__ u32 pkbf(float a, float b){
  return __builtin_amdgcn_perm(asu(b) + 0x8000u, asu(a) + 0x8000u, 0x07060302u);
}

// async global->LDS, 16B per lane; lds dest wave-uniform base (HW adds lane*16)
__device__ __forceinline__ void gl_lds16(const u16* g, u16* l) {
  __builtin_amdgcn_global_load_lds(
    (const __attribute__((address_space(1))) unsigned int*)(g),
    (__attribute__((address_space(3))) unsigned int*)(l), 16, 0, 0);
}

// ---------------- transpose+convert: in f32 [K][N] -> out bf16 [N][K] ----------------
__global__ __launch_bounds__(256) void transpose_k(const float* __restrict__ in,
                                                   u16* __restrict__ out, int K, int N)
{
  __shared__ u16 tile[32][33];
  const int tx = threadIdx.x, ty = threadIdx.y;
  const int x = blockIdx.x * 32 + tx;
  const int y0 = blockIdx.y * 32;
  #pragma unroll
  for (int j = ty; j < 32; j += 8)
    tile[j][tx] = f2b(in[(size_t)(y0 + j) * N + x]);
  __syncthreads();
  const int x2 = y0 + tx;
  const int y2 = blockIdx.x * 32;
  #pragma unroll
  for (int j = ty; j < 32; j += 8)
    out[(size_t)(y2 + j) * K + x2] = tile[tx][j];
}

// ---------------- layernorm: f32 in, bf16 out; one block per row of 1024 ----------------
__global__ __launch_bounds__(256) void ln_k(const float* __restrict__ xin,
                                            const float* __restrict__ g,
                                            const float* __restrict__ be,
                                            u16* __restrict__ out)
{
  const int row = blockIdx.x, tid = threadIdx.x;
  float4 u = *(const float4*)(xin + (size_t)row * 1024 + tid * 4);
  float v[4] = {u.x, u.y, u.z, u.w};
  float sum = v[0] + v[1] + v[2] + v[3];
  float sq  = v[0]*v[0] + v[1]*v[1] + v[2]*v[2] + v[3]*v[3];
  #pragma unroll
  for (int off = 32; off > 0; off >>= 1) {
    sum += __shfl_down(sum, off, 64);
    sq  += __shfl_down(sq,  off, 64);
  }
  __shared__ float ws1[4], ws2[4];
  const int wid = tid >> 6, lane = tid & 63;
  if (lane == 0) { ws1[wid] = sum; ws2[wid] = sq; }
  __syncthreads();
  const float tot  = ws1[0] + ws1[1] + ws1[2] + ws1[3];
  const float tot2 = ws2[0] + ws2[1] + ws2[2] + ws2[3];
  const float inv = 1.0f / 1024.0f;
  const float mu = tot * inv;
  const float var = tot2 * inv - mu * mu;
  const float rs = rsqrtf(var + 1e-5f);
  float4 gv = *(const float4*)(g  + tid * 4);
  float4 bv = *(const float4*)(be + tid * 4);
  u16 ob[4];
  ob[0] = f2b((v[0] - mu) * rs * gv.x + bv.x);
  ob[1] = f2b((v[1] - mu) * rs * gv.y + bv.y);
  ob[2] = f2b((v[2] - mu) * rs * gv.z + bv.z);
  ob[3] = f2b((v[3] - mu) * rs * gv.w + bv.w);
  uint2 o;
  o.x = (unsigned)ob[0] | ((unsigned)ob[1] << 16);
  o.y = (unsigned)ob[2] | ((unsigned)ob[3] << 16);
  *(uint2*)(out + (size_t)row * 1024 + tid * 4) = o;
}

// ---- GEMM A (m97-style gl_lds): for grids with >=2 blocks/CU ----
template<int ACT, bool RES, bool OUTF>
__global__ __launch_bounds__(256) void gemm_lds(const u16* __restrict__ A, int lda,
                                                const u16* __restrict__ Bt, int ldb,
                                                const float* __restrict__ bias,
                                                const float* __restrict__ res,
                                                void* __restrict__ Cout,
                                                int K, int ldc)
{
  __shared__ __align__(16) u16 As[128 * 64];
  __shared__ __align__(16) u16 Bs[128 * 64];
  const int tid = threadIdx.x;
  const int wid = tid >> 6, lane = tid & 63, quad = lane >> 4, ln = lane & 15;
  const int wr = wid >> 1, wc = wid & 1;
  const int m0 = blockIdx.y * 128, n0 = blockIdx.x * 128;

  f32x4 acc[4][4];
  #pragma unroll
  for (int i = 0; i < 4; ++i)
    #pragma unroll
    for (int j = 0; j < 4; ++j)
      #pragma unroll
      for (int r = 0; r < 4; ++r) acc[i][j][r] = 0.f;

  const int srow = wid * 32 + (lane >> 3);
  const int scol = (lane & 7) * 8;

  for (int k0 = 0; k0 < K; k0 += 64) {
    __syncthreads();
    #pragma unroll
    for (int i = 0; i < 4; ++i) {
      const int row = srow + i * 8;
      gl_lds16(&A [(size_t)(m0 + row) * lda + k0 + scol], &As[wid * 2048 + i * 512]);
      gl_lds16(&Bt[(size_t)(n0 + row) * ldb + k0 + scol], &Bs[wid * 2048 + i * 512]);
    }
    __syncthreads();
    #pragma unroll
    for (int ks = 0; ks < 2; ++ks) {
      s16x8 af[4], bfr[4];
      #pragma unroll
      for (int i = 0; i < 4; ++i) af[i]  = *(const s16x8*)&As[(wr*64 + i*16 + ln)*64 + ks*32 + quad*8];
      #pragma unroll
      for (int j = 0; j < 4; ++j) bfr[j] = *(const s16x8*)&Bs[(wc*64 + j*16 + ln)*64 + ks*32 + quad*8];
      #pragma unroll
      for (int i = 0; i < 4; ++i)
        #pragma unroll
        for (int j = 0; j < 4; ++j)
          acc[i][j] = __builtin_amdgcn_mfma_f32_16x16x32_bf16(af[i], bfr[j], acc[i][j], 0, 0, 0);
    }
  }
  float bv[4];
  #pragma unroll
  for (int j = 0; j < 4; ++j) bv[j] = bias ? bias[n0 + wc*64 + j*16 + ln] : 0.f;
  #pragma unroll
  for (int i = 0; i < 4; ++i) {
    #pragma unroll
    for (int r = 0; r < 4; ++r) {
      const int row = m0 + wr*64 + i*16 + quad*4 + r;
      #pragma unroll
      for (int j = 0; j < 4; ++j) {
        const int col = n0 + wc*64 + j*16 + ln;
        const size_t idx = (size_t)row * ldc + col;
        float v = acc[i][j][r] + bv[j];
        if (RES) v += res[idx];
        if (ACT == 1) v = 0.5f * v * (1.f + erff(v * 0.70710678118f));
        if (OUTF) ((float*)Cout)[idx] = v;
        else      ((u16*)Cout)[idx] = f2b(v);
      }
    }
  }
}

// ---- GEMM B v2 (latency-tolerant, for 1-block/CU grids): 512 threads (8 waves =
// 2/SIMD), 128x128 tile, LDS double-buffer + register prefetch 2 tiles deep,
// one barrier per K-iter. Grid: x = M-block (XCD L2 A-reuse), y = N-block. ----
template<int ACT, bool RES, bool OUTF>
__global__ __launch_bounds__(512) void gemm_pf2(const u16* __restrict__ A, int lda,
                                                const u16* __restrict__ Bt, int ldb,
                                                const float* __restrict__ bias,
                                                const float* __restrict__ res,
                                                void* __restrict__ Cout,
                                                int K, int ldc)
{
  __shared__ __align__(16) u16 As[2][128 * 64];
  __shared__ __align__(16) u16 Bs[2][128 * 64];
  const int tid = threadIdx.x;
  const int wid = tid >> 6, lane = tid & 63, quad = lane >> 4, ln = lane & 15;
  const int wr = wid >> 1, wc = wid & 1;     // wr 0..3 (32-row slab), wc 0..1 (64-col slab)
  const int m0 = blockIdx.x * 128, n0 = blockIdx.y * 128;

  f32x4 acc[2][4];
  #pragma unroll
  for (int i = 0; i < 2; ++i)
    #pragma unroll
    for (int j = 0; j < 4; ++j)
      #pragma unroll
      for (int r = 0; r < 4; ++r) acc[i][j][r] = 0.f;

  const int lr = tid >> 2;            // 0..127
  const int lc = (tid & 3) * 16;      // 0,16,32,48
  const u16* Ab = &A [(size_t)(m0 + lr) * lda + lc];
  const u16* Bb = &Bt[(size_t)(n0 + lr) * ldb + lc];

  s16x8 ra[2], rb[2];
  // tile 0 -> LDS buf 0 (through regs)
  ra[0] = *(const s16x8*)(Ab);     ra[1] = *(const s16x8*)(Ab + 8);
  rb[0] = *(const s16x8*)(Bb);     rb[1] = *(const s16x8*)(Bb + 8);
  *(s16x8*)&As[0][lr*64 + lc]     = ra[0];
  *(s16x8*)&As[0][lr*64 + lc + 8] = ra[1];
  *(s16x8*)&Bs[0][lr*64 + lc]     = rb[0];
  *(s16x8*)&Bs[0][lr*64 + lc + 8] = rb[1];
  const int nk = K >> 6;
  if (nk > 1) {  // prefetch tile 1 into regs
    ra[0] = *(const s16x8*)(Ab + 64);  ra[1] = *(const s16x8*)(Ab + 72);
    rb[0] = *(const s16x8*)(Bb + 64);  rb[1] = *(const s16x8*)(Bb + 72);
  }
  __syncthreads();

  for (int k = 0; k < nk; ++k) {
    // stage tile k+1 into the other buffer; issue loads for tile k+2
    if (k + 1 < nk) {
      const int p = (k + 1) & 1;
      *(s16x8*)&As[p][lr*64 + lc]     = ra[0];
      *(s16x8*)&As[p][lr*64 + lc + 8] = ra[1];
      *(s16x8*)&Bs[p][lr*64 + lc]     = rb[0];
      *(s16x8*)&Bs[p][lr*64 + lc + 8] = rb[1];
      if (k + 2 < nk) {
        const u16* An = Ab + (k + 2) * 64;
        const u16* Bn = Bb + (k + 2) * 64;
        ra[0] = *(const s16x8*)(An);  ra[1] = *(const s16x8*)(An + 8);
        rb[0] = *(const s16x8*)(Bn);  rb[1] = *(const s16x8*)(Bn + 8);
      }
    }
    // compute from buffer k&1
    const int c = k & 1;
    #pragma unroll
    for (int ks = 0; ks < 2; ++ks) {
      s16x8 af[2], bfr[4];
      #pragma unroll
      for (int i = 0; i < 2; ++i) af[i]  = *(const s16x8*)&As[c][(wr*32 + i*16 + ln)*64 + ks*32 + quad*8];
      #pragma unroll
      for (int j = 0; j < 4; ++j) bfr[j] = *(const s16x8*)&Bs[c][(wc*64 + j*16 + ln)*64 + ks*32 + quad*8];
      #pragma unroll
      for (int i = 0; i < 2; ++i)
        #pragma unroll
        for (int j = 0; j < 4; ++j)
          acc[i][j] = __builtin_amdgcn_mfma_f32_16x16x32_bf16(af[i], bfr[j], acc[i][j], 0, 0, 0);
    }
    __syncthreads();
  }

  float bv[4];
  #pragma unroll
  for (int j = 0; j < 4; ++j) bv[j] = bias ? bias[n0 + wc*64 + j*16 + ln] : 0.f;
  #pragma unroll
  for (int i = 0; i < 2; ++i) {
    #pragma unroll
    for (int r = 0; r < 4; ++r) {
      const int row = m0 + wr*32 + i*16 + quad*4 + r;
      #pragma unroll
      for (int j = 0; j < 4; ++j) {
        const int col = n0 + wc*64 + j*16 + ln;
        const size_t idx = (size_t)row * ldc + col;
        float v = acc[i][j][r] + bv[j];
        if (RES) v += res[idx];
        if (ACT == 1) v = 0.5f * v * (1.f + erff(v * 0.70710678118f));
        if (OUTF) ((float*)Cout)[idx] = v;
        else      ((u16*)Cout)[idx] = f2b(v);
      }
    }
  }
}

// ---------------- flash attention v3 (unchanged from R5) ----------------
__global__ __launch_bounds__(256) void attn_k(const u16* __restrict__ qkv,
                                              u16* __restrict__ outp)
{
  constexpr int LDK = 72;
  __shared__ __align__(16) u16 Kt[64 * LDK];
  __shared__ __align__(16) u16 Vt[64 * LDK];
  const int tid = threadIdx.x, wid = tid >> 6, lane = tid & 63;
  const int quad = lane >> 4, ln = lane & 15;
  const int qb = 31 - (blockIdx.x >> 5);
  const int bh = blockIdx.x & 31, b = bh >> 4, h = bh & 15;
  const u16* base = qkv + (size_t)b * 2048 * 3072;
  const float C = 0.18033688f;   // 0.125 * log2(e)

  const int tkr = tid >> 2, tkc = (tid & 3) * 16;
  const int qln = qb * 64 + wid * 16 + ln;

  s16x8 aQ0, aQ1;
  {
    const u16* qrow = base + (size_t)qln * 3072 + h * 64 + quad * 8;
    aQ0 = *(const s16x8*)(qrow);
    aQ1 = *(const s16x8*)(qrow + 32);
  }
  f32x4 o[4];
  float lsum = 0.f;
  #pragma unroll
  for (int dt = 0; dt < 4; ++dt)
    #pragma unroll
    for (int r = 0; r < 4; ++r) o[dt][r] = 0.f;

  for (int kt = 0; kt < qb; ++kt) {
    const int kb = kt * 64;
    __syncthreads();
    {
      const u16* krow = base + (size_t)(kb + tkr) * 3072 + 1024 + h * 64 + tkc;
      *(s16x8*)&Kt[tkr * LDK + tkc]     = *(const s16x8*)(krow);
      *(s16x8*)&Kt[tkr * LDK + tkc + 8] = *(const s16x8*)(krow + 8);
      const u16* vrow = base + (size_t)(kb + lane) * 3072 + 2048 + h * 64 + wid * 16;
      s16x8 va = *(const s16x8*)(vrow);
      s16x8 vb = *(const s16x8*)(vrow + 8);
      #pragma unroll
      for (int e = 0; e < 8; ++e) {
        Vt[(wid * 16 + e) * LDK + lane]     = (u16)va[e];
        Vt[(wid * 16 + 8 + e) * LDK + lane] = (u16)vb[e];
      }
    }
    __syncthreads();

    #pragma unroll
    for (int mt = 0; mt < 4; ++mt) {
      f32x4 s;
      #pragma unroll
      for (int r = 0; r < 4; ++r) s[r] = 0.f;
      s16x8 k0 = *(const s16x8*)&Kt[(mt*16 + ln) * LDK + quad * 8];
      s16x8 k1 = *(const s16x8*)&Kt[(mt*16 + ln) * LDK + 32 + quad * 8];
      s = __builtin_amdgcn_mfma_f32_16x16x32_bf16(k0, aQ0, s, 0, 0, 0);
      s = __builtin_amdgcn_mfma_f32_16x16x32_bf16(k1, aQ1, s, 0, 0, 0);
      float p0 = exp2f(s[0] * C), p1 = exp2f(s[1] * C);
      float p2 = exp2f(s[2] * C), p3 = exp2f(s[3] * C);
      lsum += (p0 + p1) + (p2 + p3);
      union { u32 u[2]; s16x4 v; } bp;
      bp.u[0] = pkbf(p0, p1); bp.u[1] = pkbf(p2, p3);
      #pragma unroll
      for (int dt = 0; dt < 4; ++dt) {
        s16x4 aV = *(const s16x4*)&Vt[(dt*16 + ln) * LDK + mt*16 + quad*4];
        o[dt] = __builtin_amdgcn_mfma_f32_16x16x16bf16_1k(aV, bp.v, o[dt], 0, 0, 0);
      }
    }
  }

  {
    const int kb = qb * 64;
    __syncthreads();
    {
      const u16* krow = base + (size_t)(kb + tkr) * 3072 + 1024 + h * 64 + tkc;
      *(s16x8*)&Kt[tkr * LDK + tkc]     = *(const s16x8*)(krow);
      *(s16x8*)&Kt[tkr * LDK + tkc + 8] = *(const s16x8*)(krow + 8);
      const u16* vrow = base + (size_t)(kb + lane) * 3072 + 2048 + h * 64 + wid * 16;
      s16x8 va = *(const s16x8*)(vrow);
      s16x8 vb = *(const s16x8*)(vrow + 8);
      #pragma unroll
      for (int e = 0; e < 8; ++e) {
        Vt[(wid * 16 + e) * LDK + lane]     = (u16)va[e];
        Vt[(wid * 16 + 8 + e) * LDK + lane] = (u16)vb[e];
      }
    }
    __syncthreads();

    #pragma unroll
    for (int mt = 0; mt < 4; ++mt) {
      if (mt <= wid) {
        f32x4 s;
        #pragma unroll
        for (int r = 0; r < 4; ++r) s[r] = 0.f;
        s16x8 k0 = *(const s16x8*)&Kt[(mt*16 + ln) * LDK + quad * 8];
        s16x8 k1 = *(const s16x8*)&Kt[(mt*16 + ln) * LDK + 32 + quad * 8];
        s = __builtin_amdgcn_mfma_f32_16x16x32_bf16(k0, aQ0, s, 0, 0, 0);
        s = __builtin_amdgcn_mfma_f32_16x16x32_bf16(k1, aQ1, s, 0, 0, 0);
        float p[4];
        #pragma unroll
        for (int r = 0; r < 4; ++r) {
          p[r] = exp2f(s[r] * C);
          if (mt == wid && (quad*4 + r) > ln) p[r] = 0.f;
        }
        lsum += (p[0] + p[1]) + (p[2] + p[3]);
        union { u32 u[2]; s16x4 v; } bp;
        bp.u[0] = pkbf(p[0], p[1]); bp.u[1] = pkbf(p[2], p[3]);
        #pragma unroll
        for (int dt = 0; dt < 4; ++dt) {
          s16x4 aV = *(const s16x4*)&Vt[(dt*16 + ln) * LDK + mt*16 + quad*4];
          o[dt] = __builtin_amdgcn_mfma_f32_16x16x16bf16_1k(aV, bp.v, o[dt], 0, 0, 0);
        }
      }
    }
  }

  lsum += __shfl_xor(lsum, 16, 64);
  lsum += __shfl_xor(lsum, 32, 64);
  const float inv = 1.0f / lsum;

  u16* orow = outp + (size_t)(b * 2048 + qln) * 1024 + h * 64;
  #pragma unroll
  for (int dt = 0; dt < 4; ++dt) {
    uint2 w;
    w.x = pkbf(o[dt][0] * inv, o[dt][1] * inv);
    w.y = pkbf(o[dt][2] * inv, o[dt][3] * inv);
    *(uint2*)(orow + dt*16 + quad*4) = w;
  }
}

// ---------------- launch ----------------
extern "C" void kernel_launch(void* const* d_in, const int* in_sizes, int n_in,
                              void* d_out, int out_size, void* d_ws, size_t ws_size,
                              hipStream_t stream)
{
  (void)in_sizes; (void)n_in; (void)out_size;
  const float* x      = (const float*)d_in[0];
  const float* w_qkv  = (const float*)d_in[1];
  const float* b_qkv  = (const float*)d_in[2];
  const float* w_proj = (const float*)d_in[3];
  const float* b_proj = (const float*)d_in[4];
  const float* g1     = (const float*)d_in[5];
  const float* be1    = (const float*)d_in[6];
  const float* g2     = (const float*)d_in[7];
  const float* be2    = (const float*)d_in[8];
  const float* w_fc1  = (const float*)d_in[9];
  const float* b_fc1  = (const float*)d_in[10];
  const float* w_fc2  = (const float*)d_in[11];
  const float* b_fc2  = (const float*)d_in[12];

  u16* base    = (u16*)d_ws;
  u16* hbuf    = base;                               //  [0, 8) MiB
  u16* wt_qkv  = base + (size_t) 4194304;            //  [8,14)
  u16* wt_proj = base + (size_t) 7340032;            //  [14,16)
  u16* qkvb    = base + (size_t) 8388608;            //  [16,40)  dead after attn
  float* x2f   = (float*)(base + (size_t)8388608);   //  [16,32)  after attn
  u16* wt_fc2  = base + (size_t)16777216;            //  [32,40)  after attn
  u16* wt_fc1  = base + (size_t) 4194304;            //  [8,16)   after proj
  u16* fbuf    = base + (size_t)20971520;            //  [40, 40+16/32)
  u16* attnb   = (u16*)d_out;
  float* outf  = (float*)d_out;

  dim3 tb(32, 8);

  // stage 1: LN1 + QKV
  ln_k<<<4096, 256, 0, stream>>>(x, g1, be1, hbuf);
  transpose_k<<<dim3(96, 32), tb, 0, stream>>>(w_qkv, wt_qkv, 1024, 3072);
  gemm_lds<0,false,false><<<dim3(24, 32), 256, 0, stream>>>(hbuf, 1024, wt_qkv, 1024,
                                                            b_qkv, nullptr, qkvb, 1024, 3072);
  // stage 2: attention (bf16 out into d_out)
  attn_k<<<1024, 256, 0, stream>>>(qkvb, attnb);

  // stage 3: proj + residual (f32 trunk), then LN2
  transpose_k<<<dim3(32, 128), tb, 0, stream>>>(w_fc2, wt_fc2, 4096, 1024);
  transpose_k<<<dim3(32, 32),  tb, 0, stream>>>(w_proj, wt_proj, 1024, 1024);
  gemm_pf2<0,true,true><<<dim3(32, 8), 512, 0, stream>>>(attnb, 1024, wt_proj, 1024,
                                                         b_proj, x, x2f, 1024, 1024);
  transpose_k<<<dim3(128, 32), tb, 0, stream>>>(w_fc1, wt_fc1, 1024, 4096);
  ln_k<<<4096, 256, 0, stream>>>(x2f, g2, be2, hbuf);

  if (ws_size >= (size_t)72 * 1024 * 1024) {
    // merged MLP: fbuf = [4096][4096] bf16 (32 MiB)
    gemm_lds<1,false,false><<<dim3(32, 32), 256, 0, stream>>>(hbuf, 1024, wt_fc1, 1024,
                                                              b_fc1, nullptr, fbuf, 1024, 4096);
    gemm_pf2<0,true,true><<<dim3(32, 8), 512, 0, stream>>>(fbuf, 4096, wt_fc2, 4096,
                                                           b_fc2, x2f, outf, 4096, 1024);
  } else {
    // chunked MLP (56 MiB path)
    gemm_lds<1,false,false><<<dim3(16, 32), 256, 0, stream>>>(hbuf, 1024, wt_fc1, 1024,
                                                              b_fc1, nullptr, fbuf, 1024, 2048);
    gemm_pf2<0,true,true><<<dim3(32, 8), 512, 0, stream>>>(fbuf, 2048, wt_fc2, 4096,
                                                           b_fc2, x2f, x2f, 2048, 1024);
    gemm_lds<1,false,false><<<dim3(16, 32), 256, 0, stream>>>(hbuf, 1024,
                                                              wt_fc1 + (size_t)2048*1024, 1024,
                                                              b_fc1 + 2048, nullptr, fbuf, 1024, 2048);
    gemm_pf2<0,true,true><<<dim3(32, 8), 512, 0, stream>>>(fbuf, 2048, wt_fc2 + 2048, 4096,
                                                           nullptr, x2f, outf, 2048, 1024);
  }
}

// Round 7
// 393.245 us; speedup vs baseline: 1.4691x; 1.0759x over previous
//
#include <hip/hip_runtime.h>

typedef unsigned short u16;
typedef unsigned int u32;
typedef short s16x8 __attribute__((ext_vector_type(8)));
typedef short s16x4 __attribute__((ext_vector_type(4)));
typedef float f32x4 __attribute__((ext_vector_type(4)));

__device__ __forceinline__ u16 f2b(float f){
  union { float f; unsigned int i; } v; v.f = f;
  unsigned int r = v.i + 0x7FFFu + ((v.i >> 16) & 1u);
  return (u16)(r >> 16);
}
__device__ __forceinline__ u32 asu(float f){
  union { float f; unsigned int i; } v; v.f = f; return v.i;
}
// pack two f32 -> (bf16(a) | bf16(b)<<16) via v_perm, round-half-up
__device__ __forceinline__ u32 pkbf(float a, float b){
  return __builtin_amdgcn_perm(asu(b) + 0x8000u, asu(a) + 0x8000u, 0x07060302u);
}

// async global->LDS, 16B per lane; lds dest wave-uniform base (HW adds lane*16)
__device__ __forceinline__ void gl_lds16(const u16* g, u16* l) {
  __builtin_amdgcn_global_load_lds(
    (const __attribute__((address_space(1))) unsigned int*)(g),
    (__attribute__((address_space(3))) unsigned int*)(l), 16, 0, 0);
}

// ---------------- transpose+convert: in f32 [K][N] -> out bf16 [N][K] ----------------
__global__ __launch_bounds__(256) void transpose_k(const float* __restrict__ in,
                                                   u16* __restrict__ out, int K, int N)
{
  __shared__ u16 tile[32][33];
  const int tx = threadIdx.x, ty = threadIdx.y;
  const int x = blockIdx.x * 32 + tx;
  const int y0 = blockIdx.y * 32;
  #pragma unroll
  for (int j = ty; j < 32; j += 8)
    tile[j][tx] = f2b(in[(size_t)(y0 + j) * N + x]);
  __syncthreads();
  const int x2 = y0 + tx;
  const int y2 = blockIdx.x * 32;
  #pragma unroll
  for (int j = ty; j < 32; j += 8)
    out[(size_t)(y2 + j) * K + x2] = tile[tx][j];
}

// ---------------- layernorm: f32 in, bf16 out; one block per row of 1024 ----------------
__global__ __launch_bounds__(256) void ln_k(const float* __restrict__ xin,
                                            const float* __restrict__ g,
                                            const float* __restrict__ be,
                                            u16* __restrict__ out)
{
  const int row = blockIdx.x, tid = threadIdx.x;
  float4 u = *(const float4*)(xin + (size_t)row * 1024 + tid * 4);
  float v[4] = {u.x, u.y, u.z, u.w};
  float sum = v[0] + v[1] + v[2] + v[3];
  float sq  = v[0]*v[0] + v[1]*v[1] + v[2]*v[2] + v[3]*v[3];
  #pragma unroll
  for (int off = 32; off > 0; off >>= 1) {
    sum += __shfl_down(sum, off, 64);
    sq  += __shfl_down(sq,  off, 64);
  }
  __shared__ float ws1[4], ws2[4];
  const int wid = tid >> 6, lane = tid & 63;
  if (lane == 0) { ws1[wid] = sum; ws2[wid] = sq; }
  __syncthreads();
  const float tot  = ws1[0] + ws1[1] + ws1[2] + ws1[3];
  const float tot2 = ws2[0] + ws2[1] + ws2[2] + ws2[3];
  const float inv = 1.0f / 1024.0f;
  const float mu = tot * inv;
  const float var = tot2 * inv - mu * mu;
  const float rs = rsqrtf(var + 1e-5f);
  float4 gv = *(const float4*)(g  + tid * 4);
  float4 bv = *(const float4*)(be + tid * 4);
  u16 ob[4];
  ob[0] = f2b((v[0] - mu) * rs * gv.x + bv.x);
  ob[1] = f2b((v[1] - mu) * rs * gv.y + bv.y);
  ob[2] = f2b((v[2] - mu) * rs * gv.z + bv.z);
  ob[3] = f2b((v[3] - mu) * rs * gv.w + bv.w);
  uint2 o;
  o.x = (unsigned)ob[0] | ((unsigned)ob[1] << 16);
  o.y = (unsigned)ob[2] | ((unsigned)ob[3] << 16);
  *(uint2*)(out + (size_t)row * 1024 + tid * 4) = o;
}

// ---- GEMM A (gl_lds, XOR-swizzled LDS): LDS slot (r,c) holds global (r, c^(r&7))
// (col-groups of 8 u16). Store side inverts on the GLOBAL address (per-lane);
// read side XORs the chunk index -> bank rotation, 2-way max conflicts. ----
template<int ACT, bool RES, bool OUTF>
__global__ __launch_bounds__(256) void gemm_lds(const u16* __restrict__ A, int lda,
                                                const u16* __restrict__ Bt, int ldb,
                                                const float* __restrict__ bias,
                                                const float* __restrict__ res,
                                                void* __restrict__ Cout,
                                                int K, int ldc)
{
  __shared__ __align__(16) u16 As[128 * 64];
  __shared__ __align__(16) u16 Bs[128 * 64];
  const int tid = threadIdx.x;
  const int wid = tid >> 6, lane = tid & 63, quad = lane >> 4, ln = lane & 15;
  const int wr = wid >> 1, wc = wid & 1;
  const int m0 = blockIdx.y * 128, n0 = blockIdx.x * 128;

  f32x4 acc[4][4];
  #pragma unroll
  for (int i = 0; i < 4; ++i)
    #pragma unroll
    for (int j = 0; j < 4; ++j)
      #pragma unroll
      for (int r = 0; r < 4; ++r) acc[i][j][r] = 0.f;

  const int srow = wid * 32 + (lane >> 3);                    // LDS row this lane fills
  const int scol = (((lane & 7) ^ (lane >> 3)) & 7) * 8;      // swizzle-inverted global col

  for (int k0 = 0; k0 < K; k0 += 64) {
    __syncthreads();
    #pragma unroll
    for (int i = 0; i < 4; ++i) {
      const int row = srow + i * 8;
      gl_lds16(&A [(size_t)(m0 + row) * lda + k0 + scol], &As[wid * 2048 + i * 512]);
      gl_lds16(&Bt[(size_t)(n0 + row) * ldb + k0 + scol], &Bs[wid * 2048 + i * 512]);
    }
    __syncthreads();
    #pragma unroll
    for (int ks = 0; ks < 2; ++ks) {
      const int cgx = (((4*ks + quad) ^ (ln & 7)) & 7) * 8;   // swizzled chunk for this lane
      s16x8 af[4], bfr[4];
      #pragma unroll
      for (int i = 0; i < 4; ++i) af[i]  = *(const s16x8*)&As[(wr*64 + i*16 + ln)*64 + cgx];
      #pragma unroll
      for (int j = 0; j < 4; ++j) bfr[j] = *(const s16x8*)&Bs[(wc*64 + j*16 + ln)*64 + cgx];
      #pragma unroll
      for (int i = 0; i < 4; ++i)
        #pragma unroll
        for (int j = 0; j < 4; ++j)
          acc[i][j] = __builtin_amdgcn_mfma_f32_16x16x32_bf16(af[i], bfr[j], acc[i][j], 0, 0, 0);
    }
  }
  float bv[4];
  #pragma unroll
  for (int j = 0; j < 4; ++j) bv[j] = bias ? bias[n0 + wc*64 + j*16 + ln] : 0.f;
  #pragma unroll
  for (int i = 0; i < 4; ++i) {
    #pragma unroll
    for (int r = 0; r < 4; ++r) {
      const int row = m0 + wr*64 + i*16 + quad*4 + r;
      #pragma unroll
      for (int j = 0; j < 4; ++j) {
        const int col = n0 + wc*64 + j*16 + ln;
        const size_t idx = (size_t)row * ldc + col;
        float v = acc[i][j][r] + bv[j];
        if (RES) v += res[idx];
        if (ACT == 1) v = 0.5f * v * (1.f + erff(v * 0.70710678118f));
        if (OUTF) ((float*)Cout)[idx] = v;
        else      ((u16*)Cout)[idx] = f2b(v);
      }
    }
  }
}

// ---- GEMM B v2 (latency-tolerant, 1-block/CU grids): 512 threads, 128x128 tile,
// LDS double-buffer (PADDED stride 72 -> conflict-free reads) + 2-deep register
// prefetch, one barrier per K-iter. Grid: x = M-block, y = N-block. ----
template<int ACT, bool RES, bool OUTF>
__global__ __launch_bounds__(512) void gemm_pf2(const u16* __restrict__ A, int lda,
                                                const u16* __restrict__ Bt, int ldb,
                                                const float* __restrict__ bias,
                                                const float* __restrict__ res,
                                                void* __restrict__ Cout,
                                                int K, int ldc)
{
  constexpr int LDP = 72;
  __shared__ __align__(16) u16 As[2][128 * LDP];
  __shared__ __align__(16) u16 Bs[2][128 * LDP];
  const int tid = threadIdx.x;
  const int wid = tid >> 6, lane = tid & 63, quad = lane >> 4, ln = lane & 15;
  const int wr = wid >> 1, wc = wid & 1;     // wr 0..3 (32-row slab), wc 0..1 (64-col slab)
  const int m0 = blockIdx.x * 128, n0 = blockIdx.y * 128;

  f32x4 acc[2][4];
  #pragma unroll
  for (int i = 0; i < 2; ++i)
    #pragma unroll
    for (int j = 0; j < 4; ++j)
      #pragma unroll
      for (int r = 0; r < 4; ++r) acc[i][j][r] = 0.f;

  const int lr = tid >> 2;            // 0..127
  const int lc = (tid & 3) * 16;      // 0,16,32,48
  const u16* Ab = &A [(size_t)(m0 + lr) * lda + lc];
  const u16* Bb = &Bt[(size_t)(n0 + lr) * ldb + lc];

  s16x8 ra[2], rb[2];
  ra[0] = *(const s16x8*)(Ab);     ra[1] = *(const s16x8*)(Ab + 8);
  rb[0] = *(const s16x8*)(Bb);     rb[1] = *(const s16x8*)(Bb + 8);
  *(s16x8*)&As[0][lr*LDP + lc]     = ra[0];
  *(s16x8*)&As[0][lr*LDP + lc + 8] = ra[1];
  *(s16x8*)&Bs[0][lr*LDP + lc]     = rb[0];
  *(s16x8*)&Bs[0][lr*LDP + lc + 8] = rb[1];
  const int nk = K >> 6;
  if (nk > 1) {
    ra[0] = *(const s16x8*)(Ab + 64);  ra[1] = *(const s16x8*)(Ab + 72);
    rb[0] = *(const s16x8*)(Bb + 64);  rb[1] = *(const s16x8*)(Bb + 72);
  }
  __syncthreads();

  for (int k = 0; k < nk; ++k) {
    if (k + 1 < nk) {
      const int p = (k + 1) & 1;
      *(s16x8*)&As[p][lr*LDP + lc]     = ra[0];
      *(s16x8*)&As[p][lr*LDP + lc + 8] = ra[1];
      *(s16x8*)&Bs[p][lr*LDP + lc]     = rb[0];
      *(s16x8*)&Bs[p][lr*LDP + lc + 8] = rb[1];
      if (k + 2 < nk) {
        const u16* An = Ab + (k + 2) * 64;
        const u16* Bn = Bb + (k + 2) * 64;
        ra[0] = *(const s16x8*)(An);  ra[1] = *(const s16x8*)(An + 8);
        rb[0] = *(const s16x8*)(Bn);  rb[1] = *(const s16x8*)(Bn + 8);
      }
    }
    const int c = k & 1;
    #pragma unroll
    for (int ks = 0; ks < 2; ++ks) {
      s16x8 af[2], bfr[4];
      #pragma unroll
      for (int i = 0; i < 2; ++i) af[i]  = *(const s16x8*)&As[c][(wr*32 + i*16 + ln)*LDP + ks*32 + quad*8];
      #pragma unroll
      for (int j = 0; j < 4; ++j) bfr[j] = *(const s16x8*)&Bs[c][(wc*64 + j*16 + ln)*LDP + ks*32 + quad*8];
      #pragma unroll
      for (int i = 0; i < 2; ++i)
        #pragma unroll
        for (int j = 0; j < 4; ++j)
          acc[i][j] = __builtin_amdgcn_mfma_f32_16x16x32_bf16(af[i], bfr[j], acc[i][j], 0, 0, 0);
    }
    __syncthreads();
  }

  float bv[4];
  #pragma unroll
  for (int j = 0; j < 4; ++j) bv[j] = bias ? bias[n0 + wc*64 + j*16 + ln] : 0.f;
  #pragma unroll
  for (int i = 0; i < 2; ++i) {
    #pragma unroll
    for (int r = 0; r < 4; ++r) {
      const int row = m0 + wr*32 + i*16 + quad*4 + r;
      #pragma unroll
      for (int j = 0; j < 4; ++j) {
        const int col = n0 + wc*64 + j*16 + ln;
        const size_t idx = (size_t)row * ldc + col;
        float v = acc[i][j][r] + bv[j];
        if (RES) v += res[idx];
        if (ACT == 1) v = 0.5f * v * (1.f + erff(v * 0.70710678118f));
        if (OUTF) ((float*)Cout)[idx] = v;
        else      ((u16*)Cout)[idx] = f2b(v);
      }
    }
  }
}

// ---------------- flash attention v3 (unchanged from R5) ----------------
__global__ __launch_bounds__(256) void attn_k(const u16* __restrict__ qkv,
                                              u16* __restrict__ outp)
{
  constexpr int LDK = 72;
  __shared__ __align__(16) u16 Kt[64 * LDK];
  __shared__ __align__(16) u16 Vt[64 * LDK];
  const int tid = threadIdx.x, wid = tid >> 6, lane = tid & 63;
  const int quad = lane >> 4, ln = lane & 15;
  const int qb = 31 - (blockIdx.x >> 5);
  const int bh = blockIdx.x & 31, b = bh >> 4, h = bh & 15;
  const u16* base = qkv + (size_t)b * 2048 * 3072;
  const float C = 0.18033688f;   // 0.125 * log2(e)

  const int tkr = tid >> 2, tkc = (tid & 3) * 16;
  const int qln = qb * 64 + wid * 16 + ln;

  s16x8 aQ0, aQ1;
  {
    const u16* qrow = base + (size_t)qln * 3072 + h * 64 + quad * 8;
    aQ0 = *(const s16x8*)(qrow);
    aQ1 = *(const s16x8*)(qrow + 32);
  }
  f32x4 o[4];
  float lsum = 0.f;
  #pragma unroll
  for (int dt = 0; dt < 4; ++dt)
    #pragma unroll
    for (int r = 0; r < 4; ++r) o[dt][r] = 0.f;

  for (int kt = 0; kt < qb; ++kt) {
    const int kb = kt * 64;
    __syncthreads();
    {
      const u16* krow = base + (size_t)(kb + tkr) * 3072 + 1024 + h * 64 + tkc;
      *(s16x8*)&Kt[tkr * LDK + tkc]     = *(const s16x8*)(krow);
      *(s16x8*)&Kt[tkr * LDK + tkc + 8] = *(const s16x8*)(krow + 8);
      const u16* vrow = base + (size_t)(kb + lane) * 3072 + 2048 + h * 64 + wid * 16;
      s16x8 va = *(const s16x8*)(vrow);
      s16x8 vb = *(const s16x8*)(vrow + 8);
      #pragma unroll
      for (int e = 0; e < 8; ++e) {
        Vt[(wid * 16 + e) * LDK + lane]     = (u16)va[e];
        Vt[(wid * 16 + 8 + e) * LDK + lane] = (u16)vb[e];
      }
    }
    __syncthreads();

    #pragma unroll
    for (int mt = 0; mt < 4; ++mt) {
      f32x4 s;
      #pragma unroll
      for (int r = 0; r < 4; ++r) s[r] = 0.f;
      s16x8 k0 = *(const s16x8*)&Kt[(mt*16 + ln) * LDK + quad * 8];
      s16x8 k1 = *(const s16x8*)&Kt[(mt*16 + ln) * LDK + 32 + quad * 8];
      s = __builtin_amdgcn_mfma_f32_16x16x32_bf16(k0, aQ0, s, 0, 0, 0);
      s = __builtin_amdgcn_mfma_f32_16x16x32_bf16(k1, aQ1, s, 0, 0, 0);
      float p0 = exp2f(s[0] * C), p1 = exp2f(s[1] * C);
      float p2 = exp2f(s[2] * C), p3 = exp2f(s[3] * C);
      lsum += (p0 + p1) + (p2 + p3);
      union { u32 u[2]; s16x4 v; } bp;
      bp.u[0] = pkbf(p0, p1); bp.u[1] = pkbf(p2, p3);
      #pragma unroll
      for (int dt = 0; dt < 4; ++dt) {
        s16x4 aV = *(const s16x4*)&Vt[(dt*16 + ln) * LDK + mt*16 + quad*4];
        o[dt] = __builtin_amdgcn_mfma_f32_16x16x16bf16_1k(aV, bp.v, o[dt], 0, 0, 0);
      }
    }
  }

  {
    const int kb = qb * 64;
    __syncthreads();
    {
      const u16* krow = base + (size_t)(kb + tkr) * 3072 + 1024 + h * 64 + tkc;
      *(s16x8*)&Kt[tkr * LDK + tkc]     = *(const s16x8*)(krow);
      *(s16x8*)&Kt[tkr * LDK + tkc + 8] = *(const s16x8*)(krow + 8);
      const u16* vrow = base + (size_t)(kb + lane) * 3072 + 2048 + h * 64 + wid * 16;
      s16x8 va = *(const s16x8*)(vrow);
      s16x8 vb = *(const s16x8*)(vrow + 8);
      #pragma unroll
      for (int e = 0; e < 8; ++e) {
        Vt[(wid * 16 + e) * LDK + lane]     = (u16)va[e];
        Vt[(wid * 16 + 8 + e) * LDK + lane] = (u16)vb[e];
      }
    }
    __syncthreads();

    #pragma unroll
    for (int mt = 0; mt < 4; ++mt) {
      if (mt <= wid) {
        f32x4 s;
        #pragma unroll
        for (int r = 0; r < 4; ++r) s[r] = 0.f;
        s16x8 k0 = *(const s16x8*)&Kt[(mt*16 + ln) * LDK + quad * 8];
        s16x8 k1 = *(const s16x8*)&Kt[(mt*16 + ln) * LDK + 32 + quad * 8];
        s = __builtin_amdgcn_mfma_f32_16x16x32_bf16(k0, aQ0, s, 0, 0, 0);
        s = __builtin_amdgcn_mfma_f32_16x16x32_bf16(k1, aQ1, s, 0, 0, 0);
        float p[4];
        #pragma unroll
        for (int r = 0; r < 4; ++r) {
          p[r] = exp2f(s[r] * C);
          if (mt == wid && (quad*4 + r) > ln) p[r] = 0.f;
        }
        lsum += (p[0] + p[1]) + (p[2] + p[3]);
        union { u32 u[2]; s16x4 v; } bp;
        bp.u[0] = pkbf(p[0], p[1]); bp.u[1] = pkbf(p[2], p[3]);
        #pragma unroll
        for (int dt = 0; dt < 4; ++dt) {
          s16x4 aV = *(const s16x4*)&Vt[(dt*16 + ln) * LDK + mt*16 + quad*4];
          o[dt] = __builtin_amdgcn_mfma_f32_16x16x16bf16_1k(aV, bp.v, o[dt], 0, 0, 0);
        }
      }
    }
  }

  lsum += __shfl_xor(lsum, 16, 64);
  lsum += __shfl_xor(lsum, 32, 64);
  const float inv = 1.0f / lsum;

  u16* orow = outp + (size_t)(b * 2048 + qln) * 1024 + h * 64;
  #pragma unroll
  for (int dt = 0; dt < 4; ++dt) {
    uint2 w;
    w.x = pkbf(o[dt][0] * inv, o[dt][1] * inv);
    w.y = pkbf(o[dt][2] * inv, o[dt][3] * inv);
    *(uint2*)(orow + dt*16 + quad*4) = w;
  }
}

// ---------------- launch ----------------
extern "C" void kernel_launch(void* const* d_in, const int* in_sizes, int n_in,
                              void* d_out, int out_size, void* d_ws, size_t ws_size,
                              hipStream_t stream)
{
  (void)in_sizes; (void)n_in; (void)out_size;
  const float* x      = (const float*)d_in[0];
  const float* w_qkv  = (const float*)d_in[1];
  const float* b_qkv  = (const float*)d_in[2];
  const float* w_proj = (const float*)d_in[3];
  const float* b_proj = (const float*)d_in[4];
  const float* g1     = (const float*)d_in[5];
  const float* be1    = (const float*)d_in[6];
  const float* g2     = (const float*)d_in[7];
  const float* be2    = (const float*)d_in[8];
  const float* w_fc1  = (const float*)d_in[9];
  const float* b_fc1  = (const float*)d_in[10];
  const float* w_fc2  = (const float*)d_in[11];
  const float* b_fc2  = (const float*)d_in[12];

  u16* base    = (u16*)d_ws;
  u16* hbuf    = base;                               //  [0, 8) MiB
  u16* wt_qkv  = base + (size_t) 4194304;            //  [8,14)
  u16* wt_proj = base + (size_t) 7340032;            //  [14,16)
  u16* qkvb    = base + (size_t) 8388608;            //  [16,40)  dead after attn
  float* x2f   = (float*)(base + (size_t)8388608);   //  [16,32)  after attn
  u16* wt_fc2  = base + (size_t)16777216;            //  [32,40)  after attn
  u16* wt_fc1  = base + (size_t) 4194304;            //  [8,16)   after proj
  u16* fbuf    = base + (size_t)20971520;            //  [40, 40+16/32)
  u16* attnb   = (u16*)d_out;
  float* outf  = (float*)d_out;

  dim3 tb(32, 8);

  // stage 1: LN1 + QKV
  ln_k<<<4096, 256, 0, stream>>>(x, g1, be1, hbuf);
  transpose_k<<<dim3(96, 32), tb, 0, stream>>>(w_qkv, wt_qkv, 1024, 3072);
  gemm_lds<0,false,false><<<dim3(24, 32), 256, 0, stream>>>(hbuf, 1024, wt_qkv, 1024,
                                                            b_qkv, nullptr, qkvb, 1024, 3072);
  // stage 2: attention (bf16 out into d_out)
  attn_k<<<1024, 256, 0, stream>>>(qkvb, attnb);

  // stage 3: proj + residual (f32 trunk), then LN2
  transpose_k<<<dim3(32, 128), tb, 0, stream>>>(w_fc2, wt_fc2, 4096, 1024);
  transpose_k<<<dim3(32, 32),  tb, 0, stream>>>(w_proj, wt_proj, 1024, 1024);
  gemm_pf2<0,true,true><<<dim3(32, 8), 512, 0, stream>>>(attnb, 1024, wt_proj, 1024,
                                                         b_proj, x, x2f, 1024, 1024);
  transpose_k<<<dim3(128, 32), tb, 0, stream>>>(w_fc1, wt_fc1, 1024, 4096);
  ln_k<<<4096, 256, 0, stream>>>(x2f, g2, be2, hbuf);

  if (ws_size >= (size_t)72 * 1024 * 1024) {
    // merged MLP: fbuf = [4096][4096] bf16 (32 MiB)
    gemm_lds<1,false,false><<<dim3(32, 32), 256, 0, stream>>>(hbuf, 1024, wt_fc1, 1024,
                                                              b_fc1, nullptr, fbuf, 1024, 4096);
    gemm_pf2<0,true,true><<<dim3(32, 8), 512, 0, stream>>>(fbuf, 4096, wt_fc2, 4096,
                                                           b_fc2, x2f, outf, 4096, 1024);
  } else {
    // chunked MLP (56 MiB path)
    gemm_lds<1,false,false><<<dim3(16, 32), 256, 0, stream>>>(hbuf, 1024, wt_fc1, 1024,
                                                              b_fc1, nullptr, fbuf, 1024, 2048);
    gemm_pf2<0,true,true><<<dim3(32, 8), 512, 0, stream>>>(fbuf, 2048, wt_fc2, 4096,
                                                           b_fc2, x2f, x2f, 2048, 1024);
    gemm_lds<1,false,false><<<dim3(16, 32), 256, 0, stream>>>(hbuf, 1024,
                                                              wt_fc1 + (size_t)2048*1024, 1024,
                                                              b_fc1 + 2048, nullptr, fbuf, 1024, 2048);
    gemm_pf2<0,true,true><<<dim3(32, 8), 512, 0, stream>>>(fbuf, 2048, wt_fc2 + 2048, 4096,
                                                           nullptr, x2f, outf, 2048, 1024);
  }
}

// Round 8
// 357.295 us; speedup vs baseline: 1.6170x; 1.1006x over previous
//
#include <hip/hip_runtime.h>

typedef unsigned short u16;
typedef unsigned int u32;
typedef short s16x8 __attribute__((ext_vector_type(8)));
typedef short s16x4 __attribute__((ext_vector_type(4)));
typedef float f32x4 __attribute__((ext_vector_type(4)));

__device__ __forceinline__ u16 f2b(float f){
  union { float f; unsigned int i; } v; v.f = f;
  unsigned int r = v.i + 0x7FFFu + ((v.i >> 16) & 1u);
  return (u16)(r >> 16);
}
__device__ __forceinline__ u32 asu(float f){
  union { float f; unsigned int i; } v; v.f = f; return v.i;
}
// pack two f32 -> (bf16(a) | bf16(b)<<16) via v_perm, round-half-up
__device__ __forceinline__ u32 pkbf(float a, float b){
  return __builtin_amdgcn_perm(asu(b) + 0x8000u, asu(a) + 0x8000u, 0x07060302u);
}

// async global->LDS, 16B per lane; lds dest wave-uniform base (HW adds lane*16)
__device__ __forceinline__ void gl_lds16(const u16* g, u16* l) {
  __builtin_amdgcn_global_load_lds(
    (const __attribute__((address_space(1))) unsigned int*)(g),
    (__attribute__((address_space(3))) unsigned int*)(l), 16, 0, 0);
}

// ---------------- transpose+convert: in f32 [K][N] -> out bf16 [N][K] ----------------
__global__ __launch_bounds__(256) void transpose_k(const float* __restrict__ in,
                                                   u16* __restrict__ out, int K, int N)
{
  __shared__ u16 tile[32][33];
  const int tx = threadIdx.x, ty = threadIdx.y;
  const int x = blockIdx.x * 32 + tx;
  const int y0 = blockIdx.y * 32;
  #pragma unroll
  for (int j = ty; j < 32; j += 8)
    tile[j][tx] = f2b(in[(size_t)(y0 + j) * N + x]);
  __syncthreads();
  const int x2 = y0 + tx;
  const int y2 = blockIdx.x * 32;
  #pragma unroll
  for (int j = ty; j < 32; j += 8)
    out[(size_t)(y2 + j) * K + x2] = tile[tx][j];
}

// ------- vt_k: V slice of qkv [2048 keys][64 dims] -> vtg[bh][64 dims][2048 keys] -------
__global__ __launch_bounds__(256) void vt_k(const u16* __restrict__ qkv,
                                            u16* __restrict__ vtg)
{
  __shared__ u16 tile[32][33];
  const int bh = blockIdx.z, b = bh >> 4, h = bh & 15;
  const int x0 = blockIdx.x * 32;   // dim tile (0 or 32)
  const int y0 = blockIdx.y * 32;   // key tile
  const int tx = threadIdx.x, ty = threadIdx.y;
  #pragma unroll
  for (int j = ty; j < 32; j += 8)
    tile[j][tx] = qkv[(size_t)(b * 2048 + y0 + j) * 3072 + 2048 + h * 64 + x0 + tx];
  __syncthreads();
  #pragma unroll
  for (int j = ty; j < 32; j += 8)
    vtg[((size_t)bh * 64 + x0 + j) * 2048 + y0 + tx] = tile[tx][j];
}

// ---------------- layernorm: f32 in, bf16 out; one block per row of 1024 ----------------
__global__ __launch_bounds__(256) void ln_k(const float* __restrict__ xin,
                                            const float* __restrict__ g,
                                            const float* __restrict__ be,
                                            u16* __restrict__ out)
{
  const int row = blockIdx.x, tid = threadIdx.x;
  float4 u = *(const float4*)(xin + (size_t)row * 1024 + tid * 4);
  float v[4] = {u.x, u.y, u.z, u.w};
  float sum = v[0] + v[1] + v[2] + v[3];
  float sq  = v[0]*v[0] + v[1]*v[1] + v[2]*v[2] + v[3]*v[3];
  #pragma unroll
  for (int off = 32; off > 0; off >>= 1) {
    sum += __shfl_down(sum, off, 64);
    sq  += __shfl_down(sq,  off, 64);
  }
  __shared__ float ws1[4], ws2[4];
  const int wid = tid >> 6, lane = tid & 63;
  if (lane == 0) { ws1[wid] = sum; ws2[wid] = sq; }
  __syncthreads();
  const float tot  = ws1[0] + ws1[1] + ws1[2] + ws1[3];
  const float tot2 = ws2[0] + ws2[1] + ws2[2] + ws2[3];
  const float inv = 1.0f / 1024.0f;
  const float mu = tot * inv;
  const float var = tot2 * inv - mu * mu;
  const float rs = rsqrtf(var + 1e-5f);
  float4 gv = *(const float4*)(g  + tid * 4);
  float4 bv = *(const float4*)(be + tid * 4);
  u16 ob[4];
  ob[0] = f2b((v[0] - mu) * rs * gv.x + bv.x);
  ob[1] = f2b((v[1] - mu) * rs * gv.y + bv.y);
  ob[2] = f2b((v[2] - mu) * rs * gv.z + bv.z);
  ob[3] = f2b((v[3] - mu) * rs * gv.w + bv.w);
  uint2 o;
  o.x = (unsigned)ob[0] | ((unsigned)ob[1] << 16);
  o.y = (unsigned)ob[2] | ((unsigned)ob[3] << 16);
  *(uint2*)(out + (size_t)row * 1024 + tid * 4) = o;
}

// ---- GEMM A (gl_lds, XOR-swizzled LDS; 0 conflicts measured R7) ----
template<int ACT, bool RES, bool OUTF>
__global__ __launch_bounds__(256) void gemm_lds(const u16* __restrict__ A, int lda,
                                                const u16* __restrict__ Bt, int ldb,
                                                const float* __restrict__ bias,
                                                const float* __restrict__ res,
                                                void* __restrict__ Cout,
                                                int K, int ldc)
{
  __shared__ __align__(16) u16 As[128 * 64];
  __shared__ __align__(16) u16 Bs[128 * 64];
  const int tid = threadIdx.x;
  const int wid = tid >> 6, lane = tid & 63, quad = lane >> 4, ln = lane & 15;
  const int wr = wid >> 1, wc = wid & 1;
  const int m0 = blockIdx.y * 128, n0 = blockIdx.x * 128;

  f32x4 acc[4][4];
  #pragma unroll
  for (int i = 0; i < 4; ++i)
    #pragma unroll
    for (int j = 0; j < 4; ++j)
      #pragma unroll
      for (int r = 0; r < 4; ++r) acc[i][j][r] = 0.f;

  const int srow = wid * 32 + (lane >> 3);
  const int scol = (((lane & 7) ^ (lane >> 3)) & 7) * 8;

  for (int k0 = 0; k0 < K; k0 += 64) {
    __syncthreads();
    #pragma unroll
    for (int i = 0; i < 4; ++i) {
      const int row = srow + i * 8;
      gl_lds16(&A [(size_t)(m0 + row) * lda + k0 + scol], &As[wid * 2048 + i * 512]);
      gl_lds16(&Bt[(size_t)(n0 + row) * ldb + k0 + scol], &Bs[wid * 2048 + i * 512]);
    }
    __syncthreads();
    #pragma unroll
    for (int ks = 0; ks < 2; ++ks) {
      const int cgx = (((4*ks + quad) ^ (ln & 7)) & 7) * 8;
      s16x8 af[4], bfr[4];
      #pragma unroll
      for (int i = 0; i < 4; ++i) af[i]  = *(const s16x8*)&As[(wr*64 + i*16 + ln)*64 + cgx];
      #pragma unroll
      for (int j = 0; j < 4; ++j) bfr[j] = *(const s16x8*)&Bs[(wc*64 + j*16 + ln)*64 + cgx];
      #pragma unroll
      for (int i = 0; i < 4; ++i)
        #pragma unroll
        for (int j = 0; j < 4; ++j)
          acc[i][j] = __builtin_amdgcn_mfma_f32_16x16x32_bf16(af[i], bfr[j], acc[i][j], 0, 0, 0);
    }
  }
  float bv[4];
  #pragma unroll
  for (int j = 0; j < 4; ++j) bv[j] = bias ? bias[n0 + wc*64 + j*16 + ln] : 0.f;
  #pragma unroll
  for (int i = 0; i < 4; ++i) {
    #pragma unroll
    for (int r = 0; r < 4; ++r) {
      const int row = m0 + wr*64 + i*16 + quad*4 + r;
      #pragma unroll
      for (int j = 0; j < 4; ++j) {
        const int col = n0 + wc*64 + j*16 + ln;
        const size_t idx = (size_t)row * ldc + col;
        float v = acc[i][j][r] + bv[j];
        if (RES) v += res[idx];
        if (ACT == 1) v = 0.5f * v * (1.f + erff(v * 0.70710678118f));
        if (OUTF) ((float*)Cout)[idx] = v;
        else      ((u16*)Cout)[idx] = f2b(v);
      }
    }
  }
}

// ---- GEMM B v3 (latency-tolerant, 1-block/CU grids): 512 threads, 128x128 tile,
// LDS double-buffer with XOR swizzle (conflict-free) + 2-deep register prefetch. ----
template<int ACT, bool RES, bool OUTF>
__global__ __launch_bounds__(512) void gemm_pf2(const u16* __restrict__ A, int lda,
                                                const u16* __restrict__ Bt, int ldb,
                                                const float* __restrict__ bias,
                                                const float* __restrict__ res,
                                                void* __restrict__ Cout,
                                                int K, int ldc)
{
  __shared__ __align__(16) u16 As[2][128 * 64];
  __shared__ __align__(16) u16 Bs[2][128 * 64];
  const int tid = threadIdx.x;
  const int wid = tid >> 6, lane = tid & 63, quad = lane >> 4, ln = lane & 15;
  const int wr = wid >> 1, wc = wid & 1;     // wr 0..3 (32-row slab), wc 0..1 (64-col slab)
  const int m0 = blockIdx.x * 128, n0 = blockIdx.y * 128;

  f32x4 acc[2][4];
  #pragma unroll
  for (int i = 0; i < 2; ++i)
    #pragma unroll
    for (int j = 0; j < 4; ++j)
      #pragma unroll
      for (int r = 0; r < 4; ++r) acc[i][j][r] = 0.f;

  const int lr = tid >> 2;            // 0..127
  const int lc = (tid & 3) * 16;      // chunks 2t, 2t+1
  const int s1 = (((tid & 3) * 2)     ^ (lr & 7)) * 8;   // swizzled slots
  const int s2 = (((tid & 3) * 2 + 1) ^ (lr & 7)) * 8;
  const u16* Ab = &A [(size_t)(m0 + lr) * lda + lc];
  const u16* Bb = &Bt[(size_t)(n0 + lr) * ldb + lc];

  s16x8 ra[2], rb[2];
  ra[0] = *(const s16x8*)(Ab);     ra[1] = *(const s16x8*)(Ab + 8);
  rb[0] = *(const s16x8*)(Bb);     rb[1] = *(const s16x8*)(Bb + 8);
  *(s16x8*)&As[0][lr*64 + s1] = ra[0];
  *(s16x8*)&As[0][lr*64 + s2] = ra[1];
  *(s16x8*)&Bs[0][lr*64 + s1] = rb[0];
  *(s16x8*)&Bs[0][lr*64 + s2] = rb[1];
  const int nk = K >> 6;
  if (nk > 1) {
    ra[0] = *(const s16x8*)(Ab + 64);  ra[1] = *(const s16x8*)(Ab + 72);
    rb[0] = *(const s16x8*)(Bb + 64);  rb[1] = *(const s16x8*)(Bb + 72);
  }
  __syncthreads();

  for (int k = 0; k < nk; ++k) {
    if (k + 1 < nk) {
      const int p = (k + 1) & 1;
      *(s16x8*)&As[p][lr*64 + s1] = ra[0];
      *(s16x8*)&As[p][lr*64 + s2] = ra[1];
      *(s16x8*)&Bs[p][lr*64 + s1] = rb[0];
      *(s16x8*)&Bs[p][lr*64 + s2] = rb[1];
      if (k + 2 < nk) {
        const u16* An = Ab + (k + 2) * 64;
        const u16* Bn = Bb + (k + 2) * 64;
        ra[0] = *(const s16x8*)(An);  ra[1] = *(const s16x8*)(An + 8);
        rb[0] = *(const s16x8*)(Bn);  rb[1] = *(const s16x8*)(Bn + 8);
      }
    }
    const int c = k & 1;
    #pragma unroll
    for (int ks = 0; ks < 2; ++ks) {
      const int cgx = (((4*ks + quad) ^ (ln & 7)) & 7) * 8;
      s16x8 af[2], bfr[4];
      #pragma unroll
      for (int i = 0; i < 2; ++i) af[i]  = *(const s16x8*)&As[c][(wr*32 + i*16 + ln)*64 + cgx];
      #pragma unroll
      for (int j = 0; j < 4; ++j) bfr[j] = *(const s16x8*)&Bs[c][(wc*64 + j*16 + ln)*64 + cgx];
      #pragma unroll
      for (int i = 0; i < 2; ++i)
        #pragma unroll
        for (int j = 0; j < 4; ++j)
          acc[i][j] = __builtin_amdgcn_mfma_f32_16x16x32_bf16(af[i], bfr[j], acc[i][j], 0, 0, 0);
    }
    __syncthreads();
  }

  float bv[4];
  #pragma unroll
  for (int j = 0; j < 4; ++j) bv[j] = bias ? bias[n0 + wc*64 + j*16 + ln] : 0.f;
  #pragma unroll
  for (int i = 0; i < 2; ++i) {
    #pragma unroll
    for (int r = 0; r < 4; ++r) {
      const int row = m0 + wr*32 + i*16 + quad*4 + r;
      #pragma unroll
      for (int j = 0; j < 4; ++j) {
        const int col = n0 + wc*64 + j*16 + ln;
        const size_t idx = (size_t)row * ldc + col;
        float v = acc[i][j][r] + bv[j];
        if (RES) v += res[idx];
        if (ACT == 1) v = 0.5f * v * (1.f + erff(v * 0.70710678118f));
        if (OUTF) ((float*)Cout)[idx] = v;
        else      ((u16*)Cout)[idx] = f2b(v);
      }
    }
  }
}

// ---------------- flash attention v4: gl_lds swizzled K/V staging, V pre-transposed ----------------
// grid: 1024 blocks, qb = 31 - (blk>>5) (long blocks first), bh = blk & 31.
__global__ __launch_bounds__(256) void attn_k(const u16* __restrict__ qkv,
                                              const u16* __restrict__ vtg,
                                              u16* __restrict__ outp)
{
  __shared__ __align__(16) u16 Kt[64 * 64];   // swizzled [key][dim]
  __shared__ __align__(16) u16 Vt[64 * 64];   // swizzled [dim][key]
  const int tid = threadIdx.x, wid = tid >> 6, lane = tid & 63;
  const int quad = lane >> 4, ln = lane & 15;
  const int qb = 31 - (blockIdx.x >> 5);
  const int bh = blockIdx.x & 31, b = bh >> 4, h = bh & 15;
  const u16* base = qkv + (size_t)b * 2048 * 3072;
  const u16* vbase = vtg + (size_t)bh * 64 * 2048;
  const float C = 0.18033688f;   // 0.125 * log2(e)

  // staging geometry: wave w, issue i stages rows 16w+8i+(lane>>3), slot chunk lane&7,
  // global chunk swizzle-inverted: (lane&7)^(lane>>3)
  const int grow = (lane >> 3);                     // + 16*wid + 8*i
  const int gch  = ((lane & 7) ^ (lane >> 3)) * 8;  // global chunk offset (u16)
  const int qln = qb * 64 + wid * 16 + ln;

  s16x8 aQ0, aQ1;
  {
    const u16* qrow = base + (size_t)qln * 3072 + h * 64 + quad * 8;
    aQ0 = *(const s16x8*)(qrow);
    aQ1 = *(const s16x8*)(qrow + 32);
  }
  f32x4 o[4];
  float lsum = 0.f;
  #pragma unroll
  for (int dt = 0; dt < 4; ++dt)
    #pragma unroll
    for (int r = 0; r < 4; ++r) o[dt][r] = 0.f;

  const int nkt = qb + 1;
  for (int kt = 0; kt < nkt; ++kt) {
    const int kb = kt * 64;
    __syncthreads();
    #pragma unroll
    for (int i = 0; i < 2; ++i) {
      const int r = wid * 16 + i * 8 + grow;
      gl_lds16(base  + (size_t)(kb + r) * 3072 + 1024 + h * 64 + gch, &Kt[wid * 1024 + i * 512]);
      gl_lds16(vbase + (size_t)r * 2048 + kb + gch,                   &Vt[wid * 1024 + i * 512]);
    }
    __syncthreads();

    const int mtn = (kt < qb) ? 4 : (wid + 1);   // diagonal tile: wave-uniform cut
    for (int mt = 0; mt < mtn; ++mt) {
      f32x4 s;
      #pragma unroll
      for (int r = 0; r < 4; ++r) s[r] = 0.f;
      const int krow = (mt*16 + ln) * 64;
      s16x8 k0 = *(const s16x8*)&Kt[krow + ((quad     ^ (ln & 7)) * 8)];
      s16x8 k1 = *(const s16x8*)&Kt[krow + (((4+quad) ^ (ln & 7)) * 8)];
      s = __builtin_amdgcn_mfma_f32_16x16x32_bf16(k0, aQ0, s, 0, 0, 0);
      s = __builtin_amdgcn_mfma_f32_16x16x32_bf16(k1, aQ1, s, 0, 0, 0);
      float p[4];
      #pragma unroll
      for (int r = 0; r < 4; ++r) p[r] = exp2f(s[r] * C);
      if (kt == qb && mt == wid) {   // causal mask on the diagonal 16x16, lane-local
        #pragma unroll
        for (int r = 0; r < 4; ++r) if ((quad*4 + r) > ln) p[r] = 0.f;
      }
      lsum += (p[0] + p[1]) + (p[2] + p[3]);
      union { u32 u[2]; s16x4 v; } bp;
      bp.u[0] = pkbf(p[0], p[1]); bp.u[1] = pkbf(p[2], p[3]);
      const int vch = ((2*mt + (quad >> 1)) ^ (ln & 7)) * 8 + (quad & 1) * 4;
      #pragma unroll
      for (int dt = 0; dt < 4; ++dt) {
        s16x4 aV = *(const s16x4*)&Vt[(dt*16 + ln) * 64 + vch];
        o[dt] = __builtin_amdgcn_mfma_f32_16x16x16bf16_1k(aV, bp.v, o[dt], 0, 0, 0);
      }
    }
  }

  lsum += __shfl_xor(lsum, 16, 64);
  lsum += __shfl_xor(lsum, 32, 64);
  const float inv = 1.0f / lsum;

  u16* orow = outp + (size_t)(b * 2048 + qln) * 1024 + h * 64;
  #pragma unroll
  for (int dt = 0; dt < 4; ++dt) {
    uint2 w;
    w.x = pkbf(o[dt][0] * inv, o[dt][1] * inv);
    w.y = pkbf(o[dt][2] * inv, o[dt][3] * inv);
    *(uint2*)(orow + dt*16 + quad*4) = w;
  }
}

// ---------------- launch ----------------
extern "C" void kernel_launch(void* const* d_in, const int* in_sizes, int n_in,
                              void* d_out, int out_size, void* d_ws, size_t ws_size,
                              hipStream_t stream)
{
  (void)in_sizes; (void)n_in; (void)out_size;
  const float* x      = (const float*)d_in[0];
  const float* w_qkv  = (const float*)d_in[1];
  const float* b_qkv  = (const float*)d_in[2];
  const float* w_proj = (const float*)d_in[3];
  const float* b_proj = (const float*)d_in[4];
  const float* g1     = (const float*)d_in[5];
  const float* be1    = (const float*)d_in[6];
  const float* g2     = (const float*)d_in[7];
  const float* be2    = (const float*)d_in[8];
  const float* w_fc1  = (const float*)d_in[9];
  const float* b_fc1  = (const float*)d_in[10];
  const float* w_fc2  = (const float*)d_in[11];
  const float* b_fc2  = (const float*)d_in[12];

  u16* base    = (u16*)d_ws;
  u16* hbuf    = base;                               //  [0, 8) MiB
  u16* wt_qkv  = base + (size_t) 4194304;            //  [8,14)
  u16* wt_proj = base + (size_t) 7340032;            //  [14,16)
  u16* qkvb    = base + (size_t) 8388608;            //  [16,40)  dead after attn
  float* x2f   = (float*)(base + (size_t)8388608);   //  [16,32)  after attn
  u16* wt_fc2  = base + (size_t)16777216;            //  [32,40)  after attn
  u16* wt_fc1  = base + (size_t) 4194304;            //  [8,16)   after proj
  u16* vtg     = base + (size_t)20971520;            //  [40,56)  dead after attn
  u16* fbuf    = base + (size_t)20971520;            //  [40,..)  after attn
  u16* attnb   = (u16*)d_out;
  float* outf  = (float*)d_out;

  dim3 tb(32, 8);

  // stage 1: LN1 + QKV
  ln_k<<<4096, 256, 0, stream>>>(x, g1, be1, hbuf);
  transpose_k<<<dim3(96, 32), tb, 0, stream>>>(w_qkv, wt_qkv, 1024, 3072);
  gemm_lds<0,false,false><<<dim3(24, 32), 256, 0, stream>>>(hbuf, 1024, wt_qkv, 1024,
                                                            b_qkv, nullptr, qkvb, 1024, 3072);
  // stage 2: V pre-transpose + attention (bf16 out into d_out)
  vt_k<<<dim3(2, 64, 32), tb, 0, stream>>>(qkvb, vtg);
  attn_k<<<1024, 256, 0, stream>>>(qkvb, vtg, attnb);

  // stage 3: proj + residual (f32 trunk), then LN2
  transpose_k<<<dim3(32, 128), tb, 0, stream>>>(w_fc2, wt_fc2, 4096, 1024);
  transpose_k<<<dim3(32, 32),  tb, 0, stream>>>(w_proj, wt_proj, 1024, 1024);
  gemm_pf2<0,true,true><<<dim3(32, 8), 512, 0, stream>>>(attnb, 1024, wt_proj, 1024,
                                                         b_proj, x, x2f, 1024, 1024);
  transpose_k<<<dim3(128, 32), tb, 0, stream>>>(w_fc1, wt_fc1, 1024, 4096);
  ln_k<<<4096, 256, 0, stream>>>(x2f, g2, be2, hbuf);

  if (ws_size >= (size_t)72 * 1024 * 1024) {
    // merged MLP: fbuf = [4096][4096] bf16 (32 MiB)
    gemm_lds<1,false,false><<<dim3(32, 32), 256, 0, stream>>>(hbuf, 1024, wt_fc1, 1024,
                                                              b_fc1, nullptr, fbuf, 1024, 4096);
    gemm_pf2<0,true,true><<<dim3(32, 8), 512, 0, stream>>>(fbuf, 4096, wt_fc2, 4096,
                                                           b_fc2, x2f, outf, 4096, 1024);
  } else {
    // chunked MLP (56 MiB path)
    gemm_lds<1,false,false><<<dim3(16, 32), 256, 0, stream>>>(hbuf, 1024, wt_fc1, 1024,
                                                              b_fc1, nullptr, fbuf, 1024, 2048);
    gemm_pf2<0,true,true><<<dim3(32, 8), 512, 0, stream>>>(fbuf, 2048, wt_fc2, 4096,
                                                           b_fc2, x2f, x2f, 2048, 1024);
    gemm_lds<1,false,false><<<dim3(16, 32), 256, 0, stream>>>(hbuf, 1024,
                                                              wt_fc1 + (size_t)2048*1024, 1024,
                                                              b_fc1 + 2048, nullptr, fbuf, 1024, 2048);
    gemm_pf2<0,true,true><<<dim3(32, 8), 512, 0, stream>>>(fbuf, 2048, wt_fc2 + 2048, 4096,
                                                           nullptr, x2f, outf, 2048, 1024);
  }
}

// Round 9
// 335.841 us; speedup vs baseline: 1.7202x; 1.0639x over previous
//
#include <hip/hip_runtime.h>

typedef unsigned short u16;
typedef unsigned int u32;
typedef short s16x8 __attribute__((ext_vector_type(8)));
typedef short s16x4 __attribute__((ext_vector_type(4)));
typedef float f32x4 __attribute__((ext_vector_type(4)));

__device__ __forceinline__ u16 f2b(float f){
  union { float f; unsigned int i; } v; v.f = f;
  unsigned int r = v.i + 0x7FFFu + ((v.i >> 16) & 1u);
  return (u16)(r >> 16);
}
__device__ __forceinline__ u32 asu(float f){
  union { float f; unsigned int i; } v; v.f = f; return v.i;
}
// pack two f32 -> (bf16(a) | bf16(b)<<16) via v_perm, round-half-up
__device__ __forceinline__ u32 pkbf(float a, float b){
  return __builtin_amdgcn_perm(asu(b) + 0x8000u, asu(a) + 0x8000u, 0x07060302u);
}
// fast GELU: tanh form via exp2 + rcp (8 VALU ops vs ~30 for erff).
// 0.5x(1+tanh(0.79788456(x+0.044715x^3))) == x*z/(z+1), z=exp2(x*(2.302118+0.1029451x^2))
__device__ __forceinline__ float gelu_fast(float x){
  float z = exp2f(x * (2.302118f + 0.1029451f * x * x));
  return x * z * __builtin_amdgcn_rcpf(z + 1.f);
}

// async global->LDS, 16B per lane; lds dest wave-uniform base (HW adds lane*16)
__device__ __forceinline__ void gl_lds16(const u16* g, u16* l) {
  __builtin_amdgcn_global_load_lds(
    (const __attribute__((address_space(1))) unsigned int*)(g),
    (__attribute__((address_space(3))) unsigned int*)(l), 16, 0, 0);
}

// ---------------- transpose+convert: in f32 [K][N] -> out bf16 [N][K] ----------------
__global__ __launch_bounds__(256) void transpose_k(const float* __restrict__ in,
                                                   u16* __restrict__ out, int K, int N)
{
  __shared__ u16 tile[32][33];
  const int tx = threadIdx.x, ty = threadIdx.y;
  const int x = blockIdx.x * 32 + tx;
  const int y0 = blockIdx.y * 32;
  #pragma unroll
  for (int j = ty; j < 32; j += 8)
    tile[j][tx] = f2b(in[(size_t)(y0 + j) * N + x]);
  __syncthreads();
  const int x2 = y0 + tx;
  const int y2 = blockIdx.x * 32;
  #pragma unroll
  for (int j = ty; j < 32; j += 8)
    out[(size_t)(y2 + j) * K + x2] = tile[tx][j];
}

// ------- vt_k: V slice of qkv [2048 keys][64 dims] -> vtg[bh][64 dims][2048 keys] -------
__global__ __launch_bounds__(256) void vt_k(const u16* __restrict__ qkv,
                                            u16* __restrict__ vtg)
{
  __shared__ u16 tile[32][33];
  const int bh = blockIdx.z, b = bh >> 4, h = bh & 15;
  const int x0 = blockIdx.x * 32;   // dim tile (0 or 32)
  const int y0 = blockIdx.y * 32;   // key tile
  const int tx = threadIdx.x, ty = threadIdx.y;
  #pragma unroll
  for (int j = ty; j < 32; j += 8)
    tile[j][tx] = qkv[(size_t)(b * 2048 + y0 + j) * 3072 + 2048 + h * 64 + x0 + tx];
  __syncthreads();
  #pragma unroll
  for (int j = ty; j < 32; j += 8)
    vtg[((size_t)bh * 64 + x0 + j) * 2048 + y0 + tx] = tile[tx][j];
}

// ---------------- layernorm: f32 in, bf16 out; one block per row of 1024 ----------------
__global__ __launch_bounds__(256) void ln_k(const float* __restrict__ xin,
                                            const float* __restrict__ g,
                                            const float* __restrict__ be,
                                            u16* __restrict__ out)
{
  const int row = blockIdx.x, tid = threadIdx.x;
  float4 u = *(const float4*)(xin + (size_t)row * 1024 + tid * 4);
  float v[4] = {u.x, u.y, u.z, u.w};
  float sum = v[0] + v[1] + v[2] + v[3];
  float sq  = v[0]*v[0] + v[1]*v[1] + v[2]*v[2] + v[3]*v[3];
  #pragma unroll
  for (int off = 32; off > 0; off >>= 1) {
    sum += __shfl_down(sum, off, 64);
    sq  += __shfl_down(sq,  off, 64);
  }
  __shared__ float ws1[4], ws2[4];
  const int wid = tid >> 6, lane = tid & 63;
  if (lane == 0) { ws1[wid] = sum; ws2[wid] = sq; }
  __syncthreads();
  const float tot  = ws1[0] + ws1[1] + ws1[2] + ws1[3];
  const float tot2 = ws2[0] + ws2[1] + ws2[2] + ws2[3];
  const float inv = 1.0f / 1024.0f;
  const float mu = tot * inv;
  const float var = tot2 * inv - mu * mu;
  const float rs = rsqrtf(var + 1e-5f);
  float4 gv = *(const float4*)(g  + tid * 4);
  float4 bv = *(const float4*)(be + tid * 4);
  u16 ob[4];
  ob[0] = f2b((v[0] - mu) * rs * gv.x + bv.x);
  ob[1] = f2b((v[1] - mu) * rs * gv.y + bv.y);
  ob[2] = f2b((v[2] - mu) * rs * gv.z + bv.z);
  ob[3] = f2b((v[3] - mu) * rs * gv.w + bv.w);
  uint2 o;
  o.x = (unsigned)ob[0] | ((unsigned)ob[1] << 16);
  o.y = (unsigned)ob[2] | ((unsigned)ob[3] << 16);
  *(uint2*)(out + (size_t)row * 1024 + tid * 4) = o;
}

// ---- GEMM A (gl_lds, XOR-swizzled LDS; 0 conflicts measured R7) ----
template<int ACT, bool RES, bool OUTF>
__global__ __launch_bounds__(256) void gemm_lds(const u16* __restrict__ A, int lda,
                                                const u16* __restrict__ Bt, int ldb,
                                                const float* __restrict__ bias,
                                                const float* __restrict__ res,
                                                void* __restrict__ Cout,
                                                int K, int ldc)
{
  __shared__ __align__(16) u16 As[128 * 64];
  __shared__ __align__(16) u16 Bs[128 * 64];
  const int tid = threadIdx.x;
  const int wid = tid >> 6, lane = tid & 63, quad = lane >> 4, ln = lane & 15;
  const int wr = wid >> 1, wc = wid & 1;
  const int m0 = blockIdx.y * 128, n0 = blockIdx.x * 128;

  f32x4 acc[4][4];
  #pragma unroll
  for (int i = 0; i < 4; ++i)
    #pragma unroll
    for (int j = 0; j < 4; ++j)
      #pragma unroll
      for (int r = 0; r < 4; ++r) acc[i][j][r] = 0.f;

  const int srow = wid * 32 + (lane >> 3);
  const int scol = (((lane & 7) ^ (lane >> 3)) & 7) * 8;

  for (int k0 = 0; k0 < K; k0 += 64) {
    __syncthreads();
    #pragma unroll
    for (int i = 0; i < 4; ++i) {
      const int row = srow + i * 8;
      gl_lds16(&A [(size_t)(m0 + row) * lda + k0 + scol], &As[wid * 2048 + i * 512]);
      gl_lds16(&Bt[(size_t)(n0 + row) * ldb + k0 + scol], &Bs[wid * 2048 + i * 512]);
    }
    __syncthreads();
    #pragma unroll
    for (int ks = 0; ks < 2; ++ks) {
      const int cgx = (((4*ks + quad) ^ (ln & 7)) & 7) * 8;
      s16x8 af[4], bfr[4];
      #pragma unroll
      for (int i = 0; i < 4; ++i) af[i]  = *(const s16x8*)&As[(wr*64 + i*16 + ln)*64 + cgx];
      #pragma unroll
      for (int j = 0; j < 4; ++j) bfr[j] = *(const s16x8*)&Bs[(wc*64 + j*16 + ln)*64 + cgx];
      #pragma unroll
      for (int i = 0; i < 4; ++i)
        #pragma unroll
        for (int j = 0; j < 4; ++j)
          acc[i][j] = __builtin_amdgcn_mfma_f32_16x16x32_bf16(af[i], bfr[j], acc[i][j], 0, 0, 0);
    }
  }
  float bv[4];
  #pragma unroll
  for (int j = 0; j < 4; ++j) bv[j] = bias ? bias[n0 + wc*64 + j*16 + ln] : 0.f;
  #pragma unroll
  for (int i = 0; i < 4; ++i) {
    #pragma unroll
    for (int r = 0; r < 4; ++r) {
      const int row = m0 + wr*64 + i*16 + quad*4 + r;
      #pragma unroll
      for (int j = 0; j < 4; ++j) {
        const int col = n0 + wc*64 + j*16 + ln;
        const size_t idx = (size_t)row * ldc + col;
        float v = acc[i][j][r] + bv[j];
        if (RES) v += res[idx];
        if (ACT == 1) v = gelu_fast(v);
        if (OUTF) ((float*)Cout)[idx] = v;
        else      ((u16*)Cout)[idx] = f2b(v);
      }
    }
  }
}

// ---- GEMM B v3 (latency-tolerant, 1-block/CU grids): 512 threads, 128x128 tile,
// LDS double-buffer with XOR swizzle (conflict-free) + 2-deep register prefetch. ----
template<int ACT, bool RES, bool OUTF>
__global__ __launch_bounds__(512) void gemm_pf2(const u16* __restrict__ A, int lda,
                                                const u16* __restrict__ Bt, int ldb,
                                                const float* __restrict__ bias,
                                                const float* __restrict__ res,
                                                void* __restrict__ Cout,
                                                int K, int ldc)
{
  __shared__ __align__(16) u16 As[2][128 * 64];
  __shared__ __align__(16) u16 Bs[2][128 * 64];
  const int tid = threadIdx.x;
  const int wid = tid >> 6, lane = tid & 63, quad = lane >> 4, ln = lane & 15;
  const int wr = wid >> 1, wc = wid & 1;     // wr 0..3 (32-row slab), wc 0..1 (64-col slab)
  const int m0 = blockIdx.x * 128, n0 = blockIdx.y * 128;

  f32x4 acc[2][4];
  #pragma unroll
  for (int i = 0; i < 2; ++i)
    #pragma unroll
    for (int j = 0; j < 4; ++j)
      #pragma unroll
      for (int r = 0; r < 4; ++r) acc[i][j][r] = 0.f;

  const int lr = tid >> 2;            // 0..127
  const int lc = (tid & 3) * 16;      // chunks 2t, 2t+1
  const int s1 = (((tid & 3) * 2)     ^ (lr & 7)) * 8;   // swizzled slots
  const int s2 = (((tid & 3) * 2 + 1) ^ (lr & 7)) * 8;
  const u16* Ab = &A [(size_t)(m0 + lr) * lda + lc];
  const u16* Bb = &Bt[(size_t)(n0 + lr) * ldb + lc];

  s16x8 ra[2], rb[2];
  ra[0] = *(const s16x8*)(Ab);     ra[1] = *(const s16x8*)(Ab + 8);
  rb[0] = *(const s16x8*)(Bb);     rb[1] = *(const s16x8*)(Bb + 8);
  *(s16x8*)&As[0][lr*64 + s1] = ra[0];
  *(s16x8*)&As[0][lr*64 + s2] = ra[1];
  *(s16x8*)&Bs[0][lr*64 + s1] = rb[0];
  *(s16x8*)&Bs[0][lr*64 + s2] = rb[1];
  const int nk = K >> 6;
  if (nk > 1) {
    ra[0] = *(const s16x8*)(Ab + 64);  ra[1] = *(const s16x8*)(Ab + 72);
    rb[0] = *(const s16x8*)(Bb + 64);  rb[1] = *(const s16x8*)(Bb + 72);
  }
  __syncthreads();

  for (int k = 0; k < nk; ++k) {
    if (k + 1 < nk) {
      const int p = (k + 1) & 1;
      *(s16x8*)&As[p][lr*64 + s1] = ra[0];
      *(s16x8*)&As[p][lr*64 + s2] = ra[1];
      *(s16x8*)&Bs[p][lr*64 + s1] = rb[0];
      *(s16x8*)&Bs[p][lr*64 + s2] = rb[1];
      if (k + 2 < nk) {
        const u16* An = Ab + (k + 2) * 64;
        const u16* Bn = Bb + (k + 2) * 64;
        ra[0] = *(const s16x8*)(An);  ra[1] = *(const s16x8*)(An + 8);
        rb[0] = *(const s16x8*)(Bn);  rb[1] = *(const s16x8*)(Bn + 8);
      }
    }
    const int c = k & 1;
    #pragma unroll
    for (int ks = 0; ks < 2; ++ks) {
      const int cgx = (((4*ks + quad) ^ (ln & 7)) & 7) * 8;
      s16x8 af[2], bfr[4];
      #pragma unroll
      for (int i = 0; i < 2; ++i) af[i]  = *(const s16x8*)&As[c][(wr*32 + i*16 + ln)*64 + cgx];
      #pragma unroll
      for (int j = 0; j < 4; ++j) bfr[j] = *(const s16x8*)&Bs[c][(wc*64 + j*16 + ln)*64 + cgx];
      #pragma unroll
      for (int i = 0; i < 2; ++i)
        #pragma unroll
        for (int j = 0; j < 4; ++j)
          acc[i][j] = __builtin_amdgcn_mfma_f32_16x16x32_bf16(af[i], bfr[j], acc[i][j], 0, 0, 0);
    }
    __syncthreads();
  }

  float bv[4];
  #pragma unroll
  for (int j = 0; j < 4; ++j) bv[j] = bias ? bias[n0 + wc*64 + j*16 + ln] : 0.f;
  #pragma unroll
  for (int i = 0; i < 2; ++i) {
    #pragma unroll
    for (int r = 0; r < 4; ++r) {
      const int row = m0 + wr*32 + i*16 + quad*4 + r;
      #pragma unroll
      for (int j = 0; j < 4; ++j) {
        const int col = n0 + wc*64 + j*16 + ln;
        const size_t idx = (size_t)row * ldc + col;
        float v = acc[i][j][r] + bv[j];
        if (RES) v += res[idx];
        if (ACT == 1) v = gelu_fast(v);
        if (OUTF) ((float*)Cout)[idx] = v;
        else      ((u16*)Cout)[idx] = f2b(v);
      }
    }
  }
}

// ---------------- flash attention v4: gl_lds swizzled K/V staging, V pre-transposed ----------------
// grid: 1024 blocks, qb = 31 - (blk>>5) (long blocks first), bh = blk & 31.
__global__ __launch_bounds__(256) void attn_k(const u16* __restrict__ qkv,
                                              const u16* __restrict__ vtg,
                                              u16* __restrict__ outp)
{
  __shared__ __align__(16) u16 Kt[64 * 64];   // swizzled [key][dim]
  __shared__ __align__(16) u16 Vt[64 * 64];   // swizzled [dim][key]
  const int tid = threadIdx.x, wid = tid >> 6, lane = tid & 63;
  const int quad = lane >> 4, ln = lane & 15;
  const int qb = 31 - (blockIdx.x >> 5);
  const int bh = blockIdx.x & 31, b = bh >> 4, h = bh & 15;
  const u16* base = qkv + (size_t)b * 2048 * 3072;
  const u16* vbase = vtg + (size_t)bh * 64 * 2048;
  const float C = 0.18033688f;   // 0.125 * log2(e)

  const int grow = (lane >> 3);                     // + 16*wid + 8*i
  const int gch  = ((lane & 7) ^ (lane >> 3)) * 8;  // global chunk offset (u16)
  const int qln = qb * 64 + wid * 16 + ln;

  s16x8 aQ0, aQ1;
  {
    const u16* qrow = base + (size_t)qln * 3072 + h * 64 + quad * 8;
    aQ0 = *(const s16x8*)(qrow);
    aQ1 = *(const s16x8*)(qrow + 32);
  }
  f32x4 o[4];
  float lsum = 0.f;
  #pragma unroll
  for (int dt = 0; dt < 4; ++dt)
    #pragma unroll
    for (int r = 0; r < 4; ++r) o[dt][r] = 0.f;

  const int nkt = qb + 1;
  for (int kt = 0; kt < nkt; ++kt) {
    const int kb = kt * 64;
    __syncthreads();
    #pragma unroll
    for (int i = 0; i < 2; ++i) {
      const int r = wid * 16 + i * 8 + grow;
      gl_lds16(base  + (size_t)(kb + r) * 3072 + 1024 + h * 64 + gch, &Kt[wid * 1024 + i * 512]);
      gl_lds16(vbase + (size_t)r * 2048 + kb + gch,                   &Vt[wid * 1024 + i * 512]);
    }
    __syncthreads();

    const int mtn = (kt < qb) ? 4 : (wid + 1);   // diagonal tile: wave-uniform cut
    for (int mt = 0; mt < mtn; ++mt) {
      f32x4 s;
      #pragma unroll
      for (int r = 0; r < 4; ++r) s[r] = 0.f;
      const int krow = (mt*16 + ln) * 64;
      s16x8 k0 = *(const s16x8*)&Kt[krow + ((quad     ^ (ln & 7)) * 8)];
      s16x8 k1 = *(const s16x8*)&Kt[krow + (((4+quad) ^ (ln & 7)) * 8)];
      s = __builtin_amdgcn_mfma_f32_16x16x32_bf16(k0, aQ0, s, 0, 0, 0);
      s = __builtin_amdgcn_mfma_f32_16x16x32_bf16(k1, aQ1, s, 0, 0, 0);
      float p[4];
      #pragma unroll
      for (int r = 0; r < 4; ++r) p[r] = exp2f(s[r] * C);
      if (kt == qb && mt == wid) {   // causal mask on the diagonal 16x16, lane-local
        #pragma unroll
        for (int r = 0; r < 4; ++r) if ((quad*4 + r) > ln) p[r] = 0.f;
      }
      lsum += (p[0] + p[1]) + (p[2] + p[3]);
      union { u32 u[2]; s16x4 v; } bp;
      bp.u[0] = pkbf(p[0], p[1]); bp.u[1] = pkbf(p[2], p[3]);
      const int vch = ((2*mt + (quad >> 1)) ^ (ln & 7)) * 8 + (quad & 1) * 4;
      #pragma unroll
      for (int dt = 0; dt < 4; ++dt) {
        s16x4 aV = *(const s16x4*)&Vt[(dt*16 + ln) * 64 + vch];
        o[dt] = __builtin_amdgcn_mfma_f32_16x16x16bf16_1k(aV, bp.v, o[dt], 0, 0, 0);
      }
    }
  }

  lsum += __shfl_xor(lsum, 16, 64);
  lsum += __shfl_xor(lsum, 32, 64);
  const float inv = 1.0f / lsum;

  u16* orow = outp + (size_t)(b * 2048 + qln) * 1024 + h * 64;
  #pragma unroll
  for (int dt = 0; dt < 4; ++dt) {
    uint2 w;
    w.x = pkbf(o[dt][0] * inv, o[dt][1] * inv);
    w.y = pkbf(o[dt][2] * inv, o[dt][3] * inv);
    *(uint2*)(orow + dt*16 + quad*4) = w;
  }
}

// ---------------- launch ----------------
extern "C" void kernel_launch(void* const* d_in, const int* in_sizes, int n_in,
                              void* d_out, int out_size, void* d_ws, size_t ws_size,
                              hipStream_t stream)
{
  (void)in_sizes; (void)n_in; (void)out_size;
  const float* x      = (const float*)d_in[0];
  const float* w_qkv  = (const float*)d_in[1];
  const float* b_qkv  = (const float*)d_in[2];
  const float* w_proj = (const float*)d_in[3];
  const float* b_proj = (const float*)d_in[4];
  const float* g1     = (const float*)d_in[5];
  const float* be1    = (const float*)d_in[6];
  const float* g2     = (const float*)d_in[7];
  const float* be2    = (const float*)d_in[8];
  const float* w_fc1  = (const float*)d_in[9];
  const float* b_fc1  = (const float*)d_in[10];
  const float* w_fc2  = (const float*)d_in[11];
  const float* b_fc2  = (const float*)d_in[12];

  u16* base    = (u16*)d_ws;
  u16* hbuf    = base;                               //  [0, 8) MiB
  u16* wt_qkv  = base + (size_t) 4194304;            //  [8,14)
  u16* wt_proj = base + (size_t) 7340032;            //  [14,16)
  u16* qkvb    = base + (size_t) 8388608;            //  [16,40)  dead after attn
  float* x2f   = (float*)(base + (size_t)8388608);   //  [16,32)  after attn
  u16* wt_fc2  = base + (size_t)16777216;            //  [32,40)  after attn
  u16* wt_fc1  = base + (size_t) 4194304;            //  [8,16)   after proj
  u16* vtg     = base + (size_t)20971520;            //  [40,56)  dead after attn
  u16* fbuf    = base + (size_t)20971520;            //  [40,..)  after attn
  u16* attnb   = (u16*)d_out;
  float* outf  = (float*)d_out;

  dim3 tb(32, 8);

  // stage 1: LN1 + QKV
  ln_k<<<4096, 256, 0, stream>>>(x, g1, be1, hbuf);
  transpose_k<<<dim3(96, 32), tb, 0, stream>>>(w_qkv, wt_qkv, 1024, 3072);
  gemm_lds<0,false,false><<<dim3(24, 32), 256, 0, stream>>>(hbuf, 1024, wt_qkv, 1024,
                                                            b_qkv, nullptr, qkvb, 1024, 3072);
  // stage 2: V pre-transpose + attention (bf16 out into d_out)
  vt_k<<<dim3(2, 64, 32), tb, 0, stream>>>(qkvb, vtg);
  attn_k<<<1024, 256, 0, stream>>>(qkvb, vtg, attnb);

  // stage 3: proj + residual (f32 trunk), then LN2
  transpose_k<<<dim3(32, 128), tb, 0, stream>>>(w_fc2, wt_fc2, 4096, 1024);
  transpose_k<<<dim3(32, 32),  tb, 0, stream>>>(w_proj, wt_proj, 1024, 1024);
  gemm_pf2<0,true,true><<<dim3(32, 8), 512, 0, stream>>>(attnb, 1024, wt_proj, 1024,
                                                         b_proj, x, x2f, 1024, 1024);
  transpose_k<<<dim3(128, 32), tb, 0, stream>>>(w_fc1, wt_fc1, 1024, 4096);
  ln_k<<<4096, 256, 0, stream>>>(x2f, g2, be2, hbuf);

  if (ws_size >= (size_t)72 * 1024 * 1024) {
    // merged MLP: fbuf = [4096][4096] bf16 (32 MiB)
    gemm_lds<1,false,false><<<dim3(32, 32), 256, 0, stream>>>(hbuf, 1024, wt_fc1, 1024,
                                                              b_fc1, nullptr, fbuf, 1024, 4096);
    gemm_pf2<0,true,true><<<dim3(32, 8), 512, 0, stream>>>(fbuf, 4096, wt_fc2, 4096,
                                                           b_fc2, x2f, outf, 4096, 1024);
  } else {
    // chunked MLP (56 MiB path)
    gemm_lds<1,false,false><<<dim3(16, 32), 256, 0, stream>>>(hbuf, 1024, wt_fc1, 1024,
                                                              b_fc1, nullptr, fbuf, 1024, 2048);
    gemm_pf2<0,true,true><<<dim3(32, 8), 512, 0, stream>>>(fbuf, 2048, wt_fc2, 4096,
                                                           b_fc2, x2f, x2f, 2048, 1024);
    gemm_lds<1,false,false><<<dim3(16, 32), 256, 0, stream>>>(hbuf, 1024,
                                                              wt_fc1 + (size_t)2048*1024, 1024,
                                                              b_fc1 + 2048, nullptr, fbuf, 1024, 2048);
    gemm_pf2<0,true,true><<<dim3(32, 8), 512, 0, stream>>>(fbuf, 2048, wt_fc2 + 2048, 4096,
                                                           nullptr, x2f, outf, 2048, 1024);
  }
}